// Round 8
// baseline (457.684 us; speedup 1.0000x reference)
//
#include <hip/hip_runtime.h>
#include <hip/hip_bf16.h>
#include <float.h>
#include <math.h>

// Problem constants
#define NB      4
#define QN      128
#define HID     512
#define NMEM    20000
#define MPAD    20096    // 157*128
#define NCHUNK  625
#define CHUNK   32
#define HEADS   8
#define DHEAD   64
#define TOPKK   8
#define NKV     1024   // 2*HEADS*DHEAD
#define LOGIT_SCALE 0.044194173824159216f  // 512^-0.5
#define W2LD    576    // W2buf / u_ext leading dim (512 + 1 alpha col + pad)
#define STROWS  520    // summText rows: 512 + ones row + 7 zero rows
#define LGLD    640    // logits leading dim

typedef __attribute__((ext_vector_type(8))) short bf16x8;
typedef __attribute__((ext_vector_type(4))) float f32x4;

__device__ __forceinline__ short f2bf(float f){
  __hip_bfloat16 h = __float2bfloat16(f);
  return *reinterpret_cast<short*>(&h);
}
__device__ __forceinline__ float bf2f(unsigned short s){
  __hip_bfloat16 h;
  *reinterpret_cast<unsigned short*>(&h) = s;
  return __bfloat162float(h);
}
__device__ __forceinline__ bool mask_at(const void* m, int flag, long i){
  return flag ? (((const unsigned char*)m)[i] != 0)
              : (((const int*)m)[i] != 0);
}
__device__ __forceinline__ void gload16(const void* g, void* l){
  __builtin_amdgcn_global_load_lds((const __attribute__((address_space(1))) void*)g,
                                   (__attribute__((address_space(3))) void*)l, 16, 0, 0);
}

// ---------------- setup: tiled transposes + misc + fold + vker, one launch ----------------
__global__ __launch_bounds__(256) void setup_kernel(const float* __restrict__ kvw,
                                                    const float* __restrict__ skw,
                                                    const void* __restrict__ mask,
                                                    const float* __restrict__ out_w,
                                                    const float* __restrict__ out_b,
                                                    const float* __restrict__ fc2_w,
                                                    const float* __restrict__ fc2_b,
                                                    const float* __restrict__ sq_w,
                                                    const float* __restrict__ sq_b,
                                                    const float* __restrict__ sk_b,
                                                    unsigned short* __restrict__ Bt,
                                                    float* __restrict__ skwT,
                                                    float* __restrict__ pos,
                                                    int* __restrict__ flagp,
                                                    float* __restrict__ Wf,
                                                    float* __restrict__ bfold,
                                                    float* __restrict__ W2buf,
                                                    float* __restrict__ v2,
                                                    float* __restrict__ gbuf){
  __shared__ float tile[64][65];
  int sub = blockIdx.x;
  int t = threadIdx.x;
  int c = t & 63, rbase = t >> 6;
  if (sub < 128){
    int k0 = (sub >> 4) * 64, n0 = (sub & 15) * 64;
#pragma unroll
    for (int j = 0; j < 16; ++j){
      int r = rbase + j * 4;
      tile[r][c] = kvw[(long)(k0 + r) * NKV + n0 + c];
    }
    __syncthreads();
#pragma unroll
    for (int j = 0; j < 16; ++j){
      int rn = rbase + j * 4;
      Bt[(long)(n0 + rn) * 512 + k0 + c] = (unsigned short)f2bf(tile[c][rn]);
    }
  } else if (sub < 192){
    int s = sub - 128;
    int e0 = (s >> 3) * 64, j0 = (s & 7) * 64;
#pragma unroll
    for (int j = 0; j < 16; ++j){
      int r = rbase + j * 4;
      tile[r][c] = skw[(long)(e0 + r) * 512 + j0 + c];
    }
    __syncthreads();
#pragma unroll
    for (int j = 0; j < 16; ++j){
      int rj = rbase + j * 4;
      skwT[(long)(j0 + rj) * 512 + e0 + c] = tile[c][rj];
    }
  } else if (sub < 256){
    int s = sub - 192;             // 0..63
    int cc = s >> 1;               // 0..31
    int d = (s & 1) * 256 + t;     // 0..511
    int j = (d < 256) ? d : d - 256;
    float invf = expf(-((2.0f * (float)j) / 512.0f) * 9.2103403719761836f);
    float arg = (float)(31 - cc) * invf;
    pos[cc * 512 + d] = (d < 256) ? sinf(arg) : cosf(arg);
    if (s == 0 && t == 0){
      const unsigned char* mb = (const unsigned char*)mask;
      *flagp = (mb[1] != 0) ? 1 : 0;
    }
  } else if (sub < 266){
    int s = sub - 256;             // 0..9
    int j = s >> 1;                // 0..4
    int d = (s & 1) * 256 + t;
    const float4* owr = (const float4*)(out_w + (long)d * 512);
    float acc = 0.f;
    for (int k4 = 0; k4 < 128; ++k4){
      float4 a = owr[k4];
      int k = k4 * 4;
      acc += a.x * fc2_w[k * 5 + j] + a.y * fc2_w[(k + 1) * 5 + j]
           + a.z * fc2_w[(k + 2) * 5 + j] + a.w * fc2_w[(k + 3) * 5 + j];
    }
    Wf[d * 5 + j] = acc;
    if (d == 0){
      float sb = 0.f;
      for (int k = 0; k < 512; ++k) sb += out_b[k] * fc2_w[k * 5 + j];
      bfold[j] = sb + fc2_b[j];
    }
  } else {
    int s = sub - 266;             // 0..4
    if (s < 2){
      int d = s * 256 + t;
      float acc = 0.f;
      for (int j = 0; j < 512; ++j) acc += sq_w[(long)d * 512 + j] * sk_b[j];
      W2buf[(long)d * W2LD + 512] = acc;
      for (int cc = 513; cc < W2LD; ++cc) W2buf[(long)d * W2LD + cc] = 0.f;
    } else if (s < 4){
      int e = (s - 2) * 256 + t;
      float acc = 0.f;
      for (int j = 0; j < 512; ++j) acc += skw[(long)e * 512 + j] * sq_b[j];
      v2[e] = acc;
    } else {
      __shared__ float g[256];
      g[t] = sq_b[t] * sk_b[t] + sq_b[t + 256] * sk_b[t + 256];
      __syncthreads();
      for (int d = 128; d >= 1; d >>= 1){
        if (t < d) g[t] += g[t + d];
        __syncthreads();
      }
      if (t == 0) gbuf[0] = g[0];
    }
  }
}

// ---------------- fused: memories -> summ + chunkden + bf16 (mem+pos) ----------------
__global__ __launch_bounds__(512) void prepsum_kernel(const float* __restrict__ memories,
                                                      const float* __restrict__ pos,
                                                      const void* __restrict__ mask,
                                                      const int* __restrict__ flagp,
                                                      unsigned short* __restrict__ abf_all,
                                                      float* __restrict__ summ,
                                                      float* __restrict__ chunkden){
  int n = blockIdx.x, b = blockIdx.y;
  int t = threadIdx.x;
  unsigned short* abf = abf_all ? abf_all + (long)b * MPAD * 512 : nullptr;
  long mbase = (long)b * NMEM + (long)n * CHUNK;
  int flag = *flagp;
  bool mybit = mask_at(mask, flag, mbase + (t & 31));
  unsigned long long bal = __ballot(mybit);
  unsigned int m32 = (unsigned int)bal;
  float den = (float)__popc(m32);
  int c4 = t & 127;
  int rh = t >> 7;               // 0..3
  const float* base = memories + mbase * HID;
  float4 v[8], p4[8];
#pragma unroll
  for (int j = 0; j < 8; ++j)
    v[j] = *(const float4*)(base + (long)(rh + 4 * j) * HID + c4 * 4);
#pragma unroll
  for (int j = 0; j < 8; ++j)
    p4[j] = *(const float4*)(pos + (rh + 4 * j) * HID + c4 * 4);
  if (abf){
#pragma unroll
    for (int j = 0; j < 8; ++j){
      ushort4 o;
      o.x = (unsigned short)f2bf(v[j].x + p4[j].x);
      o.y = (unsigned short)f2bf(v[j].y + p4[j].y);
      o.z = (unsigned short)f2bf(v[j].z + p4[j].z);
      o.w = (unsigned short)f2bf(v[j].w + p4[j].w);
      __builtin_nontemporal_store(*(const unsigned long long*)&o,
          (unsigned long long*)(abf + (long)(n * CHUNK + rh + 4 * j) * 512 + c4 * 4));
    }
  }
  float4 acc = {0.f, 0.f, 0.f, 0.f};
#pragma unroll
  for (int j = 0; j < 8; ++j){
    if (m32 & (1u << (rh + 4 * j))){
      acc.x += v[j].x; acc.y += v[j].y; acc.z += v[j].z; acc.w += v[j].w;
    }
  }
  __shared__ float4 red[512];
  red[t] = acc;
  __syncthreads();
  if (rh == 0){
    float4 a0 = red[t], a1 = red[t + 128], a2 = red[t + 256], a3 = red[t + 384];
    float dv = den + 1e-5f;
    float4 s4;
    s4.x = (a0.x + a1.x + a2.x + a3.x) / dv;
    s4.y = (a0.y + a1.y + a2.y + a3.y) / dv;
    s4.z = (a0.z + a1.z + a2.z + a3.z) / dv;
    s4.w = (a0.w + a1.w + a2.w + a3.w) / dv;
    *(float4*)(summ + ((long)b * NCHUNK + n) * 512 + c4 * 4) = s4;
    if (t == 0) chunkden[b * NCHUNK + n] = den;
  }
}

// ---------------- prep (fallback): (mem+pos) -> bf16 A[MPAD][512] ----------------
__global__ __launch_bounds__(256) void prep_kernel(const float* __restrict__ mem,
                                                   const float* __restrict__ pos,
                                                   unsigned short* __restrict__ Abf){
  long idx = (long)blockIdx.x * 256 + threadIdx.x;
  int r = (int)(idx >> 7);
  int cv = (int)(idx & 127) << 2;
  ushort4 o;
  if (r < NMEM){
    float4 m4 = *(const float4*)(mem + (long)r * 512 + cv);
    float4 p4 = *(const float4*)(pos + (r & 31) * 512 + cv);
    o.x = (unsigned short)f2bf(m4.x + p4.x);
    o.y = (unsigned short)f2bf(m4.y + p4.y);
    o.z = (unsigned short)f2bf(m4.z + p4.z);
    o.w = (unsigned short)f2bf(m4.w + p4.w);
  } else {
    o.x = o.y = o.z = o.w = 0;
  }
  *(ushort4*)(Abf + idx * 4) = o;
}

// ---------------- generic f32 NN GEMM: C = A[M][K] @ B[K][N] * scale ----------------
__global__ __launch_bounds__(256) void gemm_nn(const float* __restrict__ A, int lda,
                                               const float* __restrict__ B, int ldb,
                                               float* __restrict__ C, int ldc,
                                               int K, float scale){
  int tid = threadIdx.x;
  int lane = tid & 63, w = tid >> 6;
  int r0 = blockIdx.x * 16 + w * 4;
  int n  = blockIdx.y * 64 + lane;
  const float* a0 = A + (long)r0 * lda;
  const float* bp = B + n;
  float acc0 = 0.f, acc1 = 0.f, acc2 = 0.f, acc3 = 0.f;
#pragma unroll 2
  for (int k = 0; k < K; k += 4){
    float b0 = bp[(long)k * ldb];
    float b1 = bp[(long)(k + 1) * ldb];
    float b2 = bp[(long)(k + 2) * ldb];
    float b3 = bp[(long)(k + 3) * ldb];
    float4 a;
    a = *(const float4*)(a0 + k);
    acc0 += a.x * b0 + a.y * b1 + a.z * b2 + a.w * b3;
    a = *(const float4*)(a0 + lda + k);
    acc1 += a.x * b0 + a.y * b1 + a.z * b2 + a.w * b3;
    a = *(const float4*)(a0 + 2 * lda + k);
    acc2 += a.x * b0 + a.y * b1 + a.z * b2 + a.w * b3;
    a = *(const float4*)(a0 + 3 * lda + k);
    acc3 += a.x * b0 + a.y * b1 + a.z * b2 + a.w * b3;
  }
  C[(long)r0 * ldc + n]       = acc0 * scale;
  C[(long)(r0 + 1) * ldc + n] = acc1 * scale;
  C[(long)(r0 + 2) * ldc + n] = acc2 * scale;
  C[(long)(r0 + 3) * ldc + n] = acc3 * scale;
}

// ---------------- uq: u_ext = queries@W2buf (y<9) and qh = queries@q_w*0.125 (y>=9) ----------------
__global__ __launch_bounds__(256) void uq_kernel(const float* __restrict__ queries,
                                                 const float* __restrict__ W2buf,
                                                 const float* __restrict__ q_w,
                                                 float* __restrict__ u_ext,
                                                 float* __restrict__ qh){
  int y = blockIdx.y;
  const float* B; int ldb; float* C; int ldc; int nbase; float scale;
  if (y < 9){ B = W2buf; ldb = W2LD; C = u_ext; ldc = W2LD; nbase = y * 64; scale = 1.0f; }
  else      { B = q_w;   ldb = 512;  C = qh;    ldc = 512;  nbase = (y - 9) * 64; scale = 0.125f; }
  int tid = threadIdx.x;
  int lane = tid & 63, w = tid >> 6;
  int r0 = blockIdx.x * 8 + w * 2;
  int n  = nbase + lane;
  const float* a0 = queries + (long)r0 * 512;
  const float* bp = B + n;
  float acc0 = 0.f, acc1 = 0.f;
#pragma unroll 4
  for (int k = 0; k < 512; k += 4){
    float b0 = bp[(long)k * ldb];
    float b1 = bp[(long)(k + 1) * ldb];
    float b2 = bp[(long)(k + 2) * ldb];
    float b3 = bp[(long)(k + 3) * ldb];
    float4 a;
    a = *(const float4*)(a0 + k);
    acc0 += a.x * b0 + a.y * b1 + a.z * b2 + a.w * b3;
    a = *(const float4*)(a0 + 512 + k);
    acc1 += a.x * b0 + a.y * b1 + a.z * b2 + a.w * b3;
  }
  C[(long)r0 * ldc + n]       = acc0 * scale;
  C[(long)(r0 + 1) * ldc + n] = acc1 * scale;
}

// ---------------- stbeta: tiled summText transpose + extra rows + betag ----------------
__global__ __launch_bounds__(256) void stbeta_kernel(const float* __restrict__ summ,
                                                     const float* __restrict__ v2,
                                                     const float* __restrict__ gbuf,
                                                     float* __restrict__ summText,
                                                     float* __restrict__ betag){
  int blk = blockIdx.x;
  int t = threadIdx.x;
  if (blk < 320){
    __shared__ float tile[64][65];
    int b = blk / 80; int rem = blk % 80;
    int n0 = (rem / 8) * 64, e0 = (rem % 8) * 64;
    int c = t & 63, rbase = t >> 6;
#pragma unroll
    for (int j = 0; j < 16; ++j){
      int r = rbase + j * 4;       // n-offset
      int n = n0 + r;
      tile[r][c] = (n < NCHUNK) ? summ[((long)b * NCHUNK + n) * 512 + e0 + c] : 0.f;
    }
    __syncthreads();
#pragma unroll
    for (int j = 0; j < 16; ++j){
      int re = rbase + j * 4;      // e-offset
      summText[(long)b * STROWS * LGLD + (long)(e0 + re) * LGLD + n0 + c] = tile[c][re];
    }
  } else if (blk < 324){
    int b = blk - 320;
    for (int idx = t; idx < 8 * LGLD; idx += 256){
      int e = idx / LGLD, n = idx - e * LGLD;
      summText[(long)b * STROWS * LGLD + (long)(512 + e) * LGLD + n] = (e == 0) ? 1.f : 0.f;
    }
  } else {
    int bb = blk - 324;            // 0..624
    int w = t >> 6, lane = t & 63;
    int row = bb * 4 + w;          // 0..2499
    const float* r = summ + (long)row * 512;
    float s = 0.f;
#pragma unroll
    for (int c = 0; c < 8; ++c) s += r[lane + 64 * c] * v2[lane + 64 * c];
    for (int d = 32; d >= 1; d >>= 1) s += __shfl_xor(s, d, 64);
    if (lane == 0){
      int b = row / NCHUNK, n = row % NCHUNK;
      betag[b * LGLD + n] = s + gbuf[0];
    }
  }
}

// ---------------- logits (NN form): 2 rows/wave, grid (16,10,NB) ----------------
__global__ __launch_bounds__(256) void logits_nn(const float* __restrict__ u_ext,
                                                 const float* __restrict__ summText,
                                                 const float* __restrict__ betag,
                                                 const float* __restrict__ chunkden,
                                                 float* __restrict__ logits){
  int b = blockIdx.z;
  int tid = threadIdx.x;
  int lane = tid & 63, w = tid >> 6;
  int r0 = blockIdx.x * 8 + w * 2;       // i
  int n  = blockIdx.y * 64 + lane;
  const float* a0 = u_ext + ((long)b * QN + r0) * W2LD;
  const float* bp = summText + (long)b * STROWS * LGLD + n;
  float acc0 = 0.f, acc1 = 0.f;
#pragma unroll 4
  for (int k = 0; k < STROWS; k += 4){
    float b0 = bp[(long)k * LGLD];
    float b1 = bp[(long)(k + 1) * LGLD];
    float b2 = bp[(long)(k + 2) * LGLD];
    float b3 = bp[(long)(k + 3) * LGLD];
    float4 a;
    a = *(const float4*)(a0 + k);
    acc0 += a.x * b0 + a.y * b1 + a.z * b2 + a.w * b3;
    a = *(const float4*)(a0 + W2LD + k);
    acc1 += a.x * b0 + a.y * b1 + a.z * b2 + a.w * b3;
  }
  if (n < NCHUNK){
    float bet = betag[b * LGLD + n];
    bool dead = (chunkden[b * NCHUNK + n] <= 0.f);
    float v0 = (acc0 + bet) * LOGIT_SCALE;
    float v1 = (acc1 + bet) * LOGIT_SCALE;
    if (dead){ v0 = v1 = -FLT_MAX; }
    long base = ((long)b * QN + r0) * LGLD + n;
    logits[base]        = v0;
    logits[base + LGLD] = v1;
  }
}

// ---------------- top-8 + softmax weights, 4 waves per (b,i) row ----------------
__global__ __launch_bounds__(256) void topk_kernel(const float* __restrict__ logits,
                                                   int* __restrict__ topi_out,
                                                   float* __restrict__ wts_out){
  int row = blockIdx.x;   // b*128+i
  __shared__ float lds[NCHUNK];
  __shared__ float wv[4];
  __shared__ int   wi[4];
  __shared__ float topv[TOPKK];
  __shared__ int   topi[TOPKK];
  int t = threadIdx.x;
  int lane = t & 63, w = t >> 6;
  for (int idx = t; idx < NCHUNK; idx += 256) lds[idx] = logits[(long)row * LGLD + idx];
  __syncthreads();
  for (int it = 0; it < TOPKK; ++it){
    float bv = -INFINITY; int bi = 0x7fffffff;
    for (int idx = t; idx < NCHUNK; idx += 256){
      float v = lds[idx];
      if (v > bv){ bv = v; bi = idx; }
    }
    for (int d = 32; d >= 1; d >>= 1){
      float ov = __shfl_xor(bv, d, 64);
      int   oi = __shfl_xor(bi, d, 64);
      if (ov > bv || (ov == bv && oi < bi)){ bv = ov; bi = oi; }
    }
    if (lane == 0){ wv[w] = bv; wi[w] = bi; }
    __syncthreads();
    if (t == 0){
      float fb = wv[0]; int fi = wi[0];
      for (int j = 1; j < 4; ++j){
        if (wv[j] > fb || (wv[j] == fb && wi[j] < fi)){ fb = wv[j]; fi = wi[j]; }
      }
      topv[it] = fb; topi[it] = fi; lds[fi] = -INFINITY;
    }
    __syncthreads();
  }
  if (t == 0){
    float m = topv[0];
    for (int r = 1; r < TOPKK; ++r) m = fmaxf(m, topv[r]);
    float e[TOPKK], s = 0.f;
    for (int r = 0; r < TOPKK; ++r){ e[r] = expf(topv[r] - m); s += e[r]; }
    for (int r = 0; r < TOPKK; ++r){
      wts_out[(long)row * TOPKK + r] = e[r] / s;
      topi_out[(long)row * TOPKK + r] = topi[r];
    }
  }
}

// ---------------- selcompact: per batch, unique selected chunks -> cidx/pos/nc ----------------
__global__ __launch_bounds__(256) void selcompact_kernel(const int* __restrict__ ti,
                                                         int* __restrict__ cidx,
                                                         int* __restrict__ posm,
                                                         int* __restrict__ ncp){
  int b = blockIdx.x;
  __shared__ int hist[NCHUNK];
  int t = threadIdx.x;
  for (int i = t; i < NCHUNK; i += 256) hist[i] = 0;
  __syncthreads();
  for (int i = t; i < QN * TOPKK; i += 256) atomicAdd(&hist[ti[(long)b * QN * TOPKK + i]], 1);
  __syncthreads();
  if (t == 0){
    int m = 0;
    for (int n = 0; n < NCHUNK; ++n){
      if (hist[n] > 0){
        cidx[b * NCHUNK + m] = n;
        posm[b * NCHUNK + n] = m;
        ++m;
      } else {
        posm[b * NCHUNK + n] = -1;
      }
    }
    ncp[b] = m;
  }
}

// ---------------- KV GEMM over COMPACT selected chunks, dbuf, XCD-aware remap ----------------
// panel p covers compact chunk slots 4p..4p+3 (128 rows). Early-exit if 4p >= nc.
__global__ __launch_bounds__(256) void kv_gemm(const unsigned short* __restrict__ A_all,
                                               const unsigned short* __restrict__ Bt,
                                               unsigned short* __restrict__ kv_all,
                                               const int* __restrict__ cidx_all,
                                               const int* __restrict__ nc_all,
                                               int npanels){
  int L = blockIdx.x;
  int panel = ((L >> 6) << 3) | (L & 7);
  int nb = (L >> 3) & 7;
  if (panel >= npanels) return;
  int bb = panel / 157;
  int p  = panel - bb * 157;
  int nc = nc_all[bb];
  if (p * 4 >= nc) return;
  const int* cidx = cidx_all + bb * NCHUNK;
  const unsigned short* A = A_all + (size_t)bb * MPAD * 512;
  unsigned short* kvout   = kv_all + (size_t)bb * MPAD * NKV;

  __shared__ unsigned short As[2][128 * 32];
  __shared__ unsigned short Bs[2][128 * 32];
  int n0 = nb << 7;
  int tid = threadIdx.x;
  int wid = tid >> 6, lane = tid & 63;
  int wr = wid >> 1, wc = wid & 1;
  int lr = lane & 15, lg = lane >> 4;

  int srow = wid * 16 + (lane >> 2);         // 0..63
  int scol = (lane & 3) << 3;
  int slot0 = p * 4 + (srow >> 5);           // rows 0..63
  int slot1 = slot0 + 2;                     // rows 64..127
  int c0 = cidx[min(slot0, nc - 1)];
  int c1 = cidx[min(slot1, nc - 1)];
  const unsigned short* gA0 = A + (long)(c0 * CHUNK + (srow & 31)) * 512 + scol;
  const unsigned short* gA1 = A + (long)(c1 * CHUNK + (srow & 31)) * 512 + scol;
  const unsigned short* gB0 = Bt + (long)(n0 + srow) * 512 + scol;
  const unsigned short* gB1 = gB0 + 64 * 512;
  int lofs0 = (wid * 16) * 32;
  int lofs1 = (64 + wid * 16) * 32;

  f32x4 acc[4][4];
#pragma unroll
  for (int i = 0; i < 4; ++i)
#pragma unroll
    for (int j = 0; j < 4; ++j) acc[i][j] = (f32x4)0.f;

#define STAGE(B, K0) { gload16(gA0 + (K0), &As[B][lofs0]); gload16(gA1 + (K0), &As[B][lofs1]); \
                       gload16(gB0 + (K0), &Bs[B][lofs0]); gload16(gB1 + (K0), &Bs[B][lofs1]); }
#define COMPUTE(B) { bf16x8 af[4], bfv[4]; \
  _Pragma("unroll") for (int mi = 0; mi < 4; ++mi) af[mi]  = *(const bf16x8*)&As[B][(wr * 64 + mi * 16 + lr) * 32 + lg * 8]; \
  _Pragma("unroll") for (int ni = 0; ni < 4; ++ni) bfv[ni] = *(const bf16x8*)&Bs[B][(wc * 64 + ni * 16 + lr) * 32 + lg * 8]; \
  _Pragma("unroll") for (int mi = 0; mi < 4; ++mi) \
    _Pragma("unroll") for (int ni = 0; ni < 4; ++ni) \
      acc[mi][ni] = __builtin_amdgcn_mfma_f32_16x16x32_bf16(af[mi], bfv[ni], acc[mi][ni], 0, 0, 0); }

  STAGE(0, 0);
  __syncthreads();
#pragma unroll 1
  for (int t = 0; t < 16; t += 2){
    if (t + 1 < 16) STAGE(1, (t + 1) * 32);
    COMPUTE(0);
    __syncthreads();
    if (t + 2 < 16) STAGE(0, (t + 2) * 32);
    COMPUTE(1);
    __syncthreads();
  }
#undef STAGE
#undef COMPUTE

  int rbase = p * 128;
  int rowlim = nc * CHUNK;
#pragma unroll
  for (int mi = 0; mi < 4; ++mi)
#pragma unroll
    for (int ni = 0; ni < 4; ++ni)
#pragma unroll
      for (int rr = 0; rr < 4; ++rr){
        int gr = rbase + wr * 64 + mi * 16 + lg * 4 + rr;
        int gn = n0 + wc * 64 + ni * 16 + lr;
        if (gr < rowlim)
          kvout[(long)gr * NKV + gn] = (unsigned short)f2bf(acc[mi][ni][rr]);
      }
}

// ---------------- attention (compact kv rows via posm); bb_arg<0 => batched ----------------
__global__ __launch_bounds__(256) void attn_kernel(const float* __restrict__ qh,
                                                   const unsigned short* __restrict__ kv,
                                                   const int* __restrict__ topidx,
                                                   const float* __restrict__ wts,
                                                   const int* __restrict__ posm,
                                                   const void* __restrict__ mask,
                                                   const int* __restrict__ flagp,
                                                   float* __restrict__ osc,
                                                   int bb_arg){
  int bx = blockIdx.x;
  int bb, rem;
  const unsigned short* kvb;
  if (bb_arg < 0){
    bb = bx >> 10; rem = bx & 1023;
    kvb = kv + (size_t)bb * MPAD * NKV;
  } else {
    bb = bb_arg; rem = bx;
    kvb = kv;
  }
  int i = rem >> 3, k = rem & 7;
  int t = threadIdx.x;
  __shared__ float qs[HID];
  __shared__ float att[HEADS][CHUNK + 1];
  int flag = *flagp;
  long sel = ((long)(bb * QN + i)) * TOPKK + k;
  int chunk = topidx[sel];
  int cm = posm[bb * NCHUNK + chunk];
  float w8 = wts[sel];
  const float* qrow = qh + ((long)(bb * QN + i)) * HID;
  qs[t] = qrow[t]; qs[t + 256] = qrow[t + 256];
  __syncthreads();
  int h = t >> 5, c = t & 31;
  const unsigned short* krow = kvb + ((long)(cm * CHUNK + c)) * NKV + h * DHEAD;
  float s = 0.f;
#pragma unroll
  for (int e8 = 0; e8 < 8; ++e8){
    bf16x8 k8 = *(const bf16x8*)(krow + e8 * 8);
#pragma unroll
    for (int j = 0; j < 8; ++j) s += qs[h * DHEAD + e8 * 8 + j] * bf2f((unsigned short)k8[j]);
  }
  bool mv = mask_at(mask, flag, (long)bb * NMEM + (long)chunk * CHUNK + c);
  if (!mv) s = -FLT_MAX;
  float m = s;
  for (int d = 16; d >= 1; d >>= 1) m = fmaxf(m, __shfl_xor(m, d, 32));
  float p = expf(s - m);
  float su = p;
  for (int d = 16; d >= 1; d >>= 1) su += __shfl_xor(su, d, 32);
  att[h][c] = p / su;
  __syncthreads();
  int e0 = (t & 31) * 2;
  float o0 = 0.f, o1 = 0.f;
#pragma unroll 8
  for (int c2 = 0; c2 < CHUNK; ++c2){
    float a = att[h][c2];
    unsigned int pv = *(const unsigned int*)(kvb + ((long)(cm * CHUNK + c2)) * NKV + 512 + h * DHEAD + e0);
    o0 += a * bf2f((unsigned short)(pv & 0xffff));
    o1 += a * bf2f((unsigned short)(pv >> 16));
  }
  long ob = (((long)(bb * QN + i) * TOPKK) + k) * HID + h * DHEAD + e0;
  osc[ob]     = o0 * w8;
  osc[ob + 1] = o1 * w8;
}

// ---------------- final: reduce over k, then @ (out_w@fc2_w) + folded bias ----------------
__global__ __launch_bounds__(512) void final_kernel(const float* __restrict__ osc,
                                                    const float* __restrict__ Wf,
                                                    const float* __restrict__ bfold,
                                                    float* __restrict__ out){
  int bi = blockIdx.x;   // b*128+i
  int t = threadIdx.x;
  __shared__ float lds[HID];
  float s = 0.f;
  for (int k = 0; k < TOPKK; ++k) s += osc[(((long)bi * TOPKK) + k) * HID + t];
  lds[t] = s;
  __syncthreads();
  int w = t >> 6, lane = t & 63;
  if (w < 5){
    float a = 0.f;
#pragma unroll
    for (int c = 0; c < 8; ++c) a += lds[lane + 64 * c] * Wf[(lane + 64 * c) * 5 + w];
    for (int d = 32; d >= 1; d >>= 1) a += __shfl_xor(a, d, 64);
    if (lane == 0) out[bi * 5 + w] = a + bfold[w];
  }
}

extern "C" void kernel_launch(void* const* d_in, const int* in_sizes, int n_in,
                              void* d_out, int out_size, void* d_ws, size_t ws_size,
                              hipStream_t stream) {
  const float* queries  = (const float*)d_in[1];
  const float* memories = (const float*)d_in[2];
  const void*  mask     = d_in[3];
  const float* sq_w = (const float*)d_in[10];
  const float* sq_b = (const float*)d_in[11];
  const float* sk_w = (const float*)d_in[12];
  const float* sk_b = (const float*)d_in[13];
  const float* q_w  = (const float*)d_in[14];
  const float* kv_w = (const float*)d_in[15];
  const float* out_w = (const float*)d_in[16];
  const float* out_b = (const float*)d_in[17];
  const float* fc2_w = (const float*)d_in[18];
  const float* fc2_b = (const float*)d_in[19];
  float* out = (float*)d_out;

  char* ws = (char*)d_ws;
  size_t o_sum  = 0;                        // 5,120,000
  size_t o_den  = o_sum + 5120000;          // 10,240
  size_t o_pos  = o_den + 10240;            // 65,536
  size_t o_wf   = o_pos + 65536;            // 10,240
  size_t o_bf   = o_wf  + 10240;            // 512
  size_t o_ti   = o_bf  + 512;              // 16,384
  size_t o_wt   = o_ti  + 16384;            // 16,384
  size_t o_flag = o_wt  + 16384;            // 512
  size_t o_cid  = o_flag + 512;             // 10,240  (cidx 4x625)
  size_t o_pm   = o_cid + 10240;            // 10,240  (posm 4x625)
  size_t o_nc   = o_pm  + 10240;            // 512     (nc 4)
  size_t o_qh   = o_nc  + 512;              // 1,048,576
  size_t o_w2   = o_qh  + 1048576;          // 1,179,648
  size_t o_uex  = o_w2  + 1179648;          // 1,179,648
  size_t o_st   = o_uex + 1179648;          // 5,324,800
  size_t o_bg   = o_st  + 5324800;          // 10,240
  size_t o_v2   = o_bg  + 10240;            // 2,048
  size_t o_gm   = o_v2  + 2048;             // 512
  size_t o_lg   = o_gm  + 512;              // 1,310,720
  size_t o_osc  = o_lg  + 1310720;          // 8,388,608
  size_t o_skt  = o_osc + 8388608;          // 1,048,576
  size_t o_abf  = o_skt + 1048576;

  const size_t ABF_ONE = (size_t)MPAD * 512 * 2;          // 20,578,304
  const size_t ABF_ALL = ABF_ONE * NB;                    // 82,313,216
  const size_t KV_ONE  = (size_t)MPAD * NKV * 2;          // 41,156,608
  size_t need_fused   = o_abf + ABF_ALL + 1048576 + KV_ONE;
  size_t need_batched = o_abf + ABF_ALL + 1048576 + KV_ONE * NB;
  bool fused   = (ws_size >= need_fused);
  bool batched = (ws_size >= need_batched);
  size_t abf_bytes = fused ? ABF_ALL : ABF_ONE;
  size_t o_btw = o_abf + abf_bytes;
  size_t o_kv  = o_btw + 1048576;

  float* summ  = (float*)(ws + o_sum);
  float* den   = (float*)(ws + o_den);
  float* pos   = (float*)(ws + o_pos);
  float* Wf    = (float*)(ws + o_wf);
  float* bfold = (float*)(ws + o_bf);
  int*   ti    = (int*)  (ws + o_ti);
  float* wt    = (float*)(ws + o_wt);
  int*   flagp = (int*)  (ws + o_flag);
  int*   cidx  = (int*)  (ws + o_cid);
  int*   posm  = (int*)  (ws + o_pm);
  int*   ncp   = (int*)  (ws + o_nc);
  float* qh    = (float*)(ws + o_qh);
  float* W2buf = (float*)(ws + o_w2);
  float* u_ext = (float*)(ws + o_uex);
  float* summText = (float*)(ws + o_st);
  float* betag = (float*)(ws + o_bg);
  float* v2    = (float*)(ws + o_v2);
  float* gbuf  = (float*)(ws + o_gm);
  float* logit = (float*)(ws + o_lg);
  float* osc   = (float*)(ws + o_osc);
  float* skwT  = (float*)(ws + o_skt);
  unsigned short* abf   = (unsigned short*)(ws + o_abf);
  unsigned short* btw   = (unsigned short*)(ws + o_btw);
  unsigned short* kvbuf = (unsigned short*)(ws + o_kv);

  setup_kernel<<<dim3(271), dim3(256), 0, stream>>>(
      kv_w, sk_w, mask, out_w, out_b, fc2_w, fc2_b, sq_w, sq_b, sk_b,
      btw, skwT, pos, flagp, Wf, bfold, W2buf, v2, gbuf);

  prepsum_kernel<<<dim3(NCHUNK, NB), dim3(512), 0, stream>>>(
      memories, pos, mask, flagp, fused ? abf : nullptr, summ, den);

  // selection path (f32-exact)
  gemm_nn<<<dim3(32, 8), dim3(256), 0, stream>>>(sq_w, 512, skwT, 512, W2buf, W2LD, 512, 1.0f);
  uq_kernel<<<dim3(64, 17), dim3(256), 0, stream>>>(queries, W2buf, q_w, u_ext, qh);
  stbeta_kernel<<<dim3(949), dim3(256), 0, stream>>>(summ, v2, gbuf, summText, betag);
  logits_nn<<<dim3(16, 10, NB), dim3(256), 0, stream>>>(u_ext, summText, betag, den, logit);
  topk_kernel<<<dim3(NB * QN), dim3(256), 0, stream>>>(logit, ti, wt);
  selcompact_kernel<<<dim3(NB), dim3(256), 0, stream>>>(ti, cidx, posm, ncp);

  if (batched){
    kv_gemm<<<dim3(((NB * 157 + 7) / 8) * 64), dim3(256), 0, stream>>>(
        abf, btw, kvbuf, cidx, ncp, NB * 157);
    attn_kernel<<<dim3(NB * QN * TOPKK), dim3(256), 0, stream>>>(
        qh, kvbuf, ti, wt, posm, mask, flagp, osc, -1);
  } else {
    for (int bb = 0; bb < NB; ++bb){
      const unsigned short* Ab;
      if (fused){
        Ab = abf + (size_t)bb * MPAD * 512;
      } else {
        prep_kernel<<<dim3(10048), dim3(256), 0, stream>>>(memories + (long)bb * NMEM * HID, pos, abf);
        Ab = abf;
      }
      kv_gemm<<<dim3(((157 + 7) / 8) * 64), dim3(256), 0, stream>>>(
          Ab, btw, kvbuf, cidx + bb * NCHUNK, ncp + bb, 157);
      attn_kernel<<<dim3(QN * TOPKK), dim3(256), 0, stream>>>(
          qh, kvbuf, ti, wt, posm + bb * NCHUNK - (size_t)bb * NCHUNK + bb * NCHUNK, mask, flagp, osc, bb);
    }
  }
  final_kernel<<<dim3(NB * QN), dim3(512), 0, stream>>>(osc, Wf, bfold, out);
}

// Round 9
// 380.597 us; speedup vs baseline: 1.2025x; 1.2025x over previous
//
#include <hip/hip_runtime.h>
#include <hip/hip_bf16.h>
#include <float.h>
#include <math.h>

// Problem constants
#define NB      4
#define QN      128
#define HID     512
#define NMEM    20000
#define MPAD    20096    // 157*128
#define NCHUNK  625
#define CHUNK   32
#define HEADS   8
#define DHEAD   64
#define TOPKK   8
#define NKV     1024   // 2*HEADS*DHEAD
#define KVLD    640    // kv GEMM output ld: 512 K cols + 40 G cols + pad
#define LOGIT_SCALE 0.044194173824159216f  // 512^-0.5
#define W2LD    576    // W2buf / u_ext leading dim (512 + 1 alpha col + pad)
#define STROWS  520    // summText rows: 512 + ones row + 7 zero rows
#define LGLD    640    // logits leading dim

typedef __attribute__((ext_vector_type(8))) short bf16x8;
typedef __attribute__((ext_vector_type(4))) float f32x4;

__device__ __forceinline__ short f2bf(float f){
  __hip_bfloat16 h = __float2bfloat16(f);
  return *reinterpret_cast<short*>(&h);
}
__device__ __forceinline__ float bf2f(unsigned short s){
  __hip_bfloat16 h;
  *reinterpret_cast<unsigned short*>(&h) = s;
  return __bfloat162float(h);
}
__device__ __forceinline__ bool mask_at(const void* m, int flag, long i){
  return flag ? (((const unsigned char*)m)[i] != 0)
              : (((const int*)m)[i] != 0);
}
__device__ __forceinline__ void gload16(const void* g, void* l){
  __builtin_amdgcn_global_load_lds((const __attribute__((address_space(1))) void*)g,
                                   (__attribute__((address_space(3))) void*)l, 16, 0, 0);
}

// ---------------- setup: tiled transposes + misc + fold + vker, one launch ----------------
__global__ __launch_bounds__(256) void setup_kernel(const float* __restrict__ kvw,
                                                    const float* __restrict__ skw,
                                                    const void* __restrict__ mask,
                                                    const float* __restrict__ out_w,
                                                    const float* __restrict__ out_b,
                                                    const float* __restrict__ fc2_w,
                                                    const float* __restrict__ fc2_b,
                                                    const float* __restrict__ sq_w,
                                                    const float* __restrict__ sq_b,
                                                    const float* __restrict__ sk_b,
                                                    unsigned short* __restrict__ Bt,
                                                    float* __restrict__ skwT,
                                                    float* __restrict__ pos,
                                                    int* __restrict__ flagp,
                                                    float* __restrict__ Wf,
                                                    float* __restrict__ bfold,
                                                    float* __restrict__ W2buf,
                                                    float* __restrict__ v2,
                                                    float* __restrict__ gbuf){
  __shared__ float tile[64][65];
  int sub = blockIdx.x;
  int t = threadIdx.x;
  int c = t & 63, rbase = t >> 6;
  if (sub < 64){
    // K-half transpose: Bt[n][k] = kv_w[k][n] for n<512 (8 n-tiles x 8 k-tiles)
    int k0 = (sub >> 3) * 64, n0 = (sub & 7) * 64;
#pragma unroll
    for (int j = 0; j < 16; ++j){
      int r = rbase + j * 4;
      tile[r][c] = kvw[(long)(k0 + r) * NKV + n0 + c];
    }
    __syncthreads();
#pragma unroll
    for (int j = 0; j < 16; ++j){
      int rn = rbase + j * 4;
      Bt[(long)(n0 + rn) * 512 + k0 + c] = (unsigned short)f2bf(tile[c][rn]);
    }
  } else if (sub < 128){
    int s = sub - 64;
    int e0 = (s >> 3) * 64, j0 = (s & 7) * 64;
#pragma unroll
    for (int j = 0; j < 16; ++j){
      int r = rbase + j * 4;
      tile[r][c] = skw[(long)(e0 + r) * 512 + j0 + c];
    }
    __syncthreads();
#pragma unroll
    for (int j = 0; j < 16; ++j){
      int rj = rbase + j * 4;
      skwT[(long)(j0 + rj) * 512 + e0 + c] = tile[c][rj];
    }
  } else if (sub < 192){
    int s = sub - 128;             // 0..63
    int cc = s >> 1;               // 0..31
    int d = (s & 1) * 256 + t;     // 0..511
    int j = (d < 256) ? d : d - 256;
    float invf = expf(-((2.0f * (float)j) / 512.0f) * 9.2103403719761836f);
    float arg = (float)(31 - cc) * invf;
    pos[cc * 512 + d] = (d < 256) ? sinf(arg) : cosf(arg);
    if (s == 0 && t == 0){
      const unsigned char* mb = (const unsigned char*)mask;
      *flagp = (mb[1] != 0) ? 1 : 0;
    }
  } else if (sub < 202){
    int s = sub - 192;             // 0..9
    int j = s >> 1;                // 0..4
    int d = (s & 1) * 256 + t;
    const float4* owr = (const float4*)(out_w + (long)d * 512);
    float acc = 0.f;
    for (int k4 = 0; k4 < 128; ++k4){
      float4 a = owr[k4];
      int k = k4 * 4;
      acc += a.x * fc2_w[k * 5 + j] + a.y * fc2_w[(k + 1) * 5 + j]
           + a.z * fc2_w[(k + 2) * 5 + j] + a.w * fc2_w[(k + 3) * 5 + j];
    }
    Wf[d * 5 + j] = acc;
    if (d == 0){
      float sb = 0.f;
      for (int k = 0; k < 512; ++k) sb += out_b[k] * fc2_w[k * 5 + j];
      bfold[j] = sb + fc2_b[j];
    }
  } else {
    int s = sub - 202;             // 0..4
    if (s < 2){
      int d = s * 256 + t;
      float acc = 0.f;
      for (int j = 0; j < 512; ++j) acc += sq_w[(long)d * 512 + j] * sk_b[j];
      W2buf[(long)d * W2LD + 512] = acc;
      for (int cc = 513; cc < W2LD; ++cc) W2buf[(long)d * W2LD + cc] = 0.f;
    } else if (s < 4){
      int e = (s - 2) * 256 + t;
      float acc = 0.f;
      for (int j = 0; j < 512; ++j) acc += skw[(long)e * 512 + j] * sq_b[j];
      v2[e] = acc;
    } else {
      __shared__ float g[256];
      g[t] = sq_b[t] * sk_b[t] + sq_b[t + 256] * sk_b[t + 256];
      __syncthreads();
      for (int d = 128; d >= 1; d >>= 1){
        if (t < d) g[t] += g[t + d];
        __syncthreads();
      }
      if (t == 0) gbuf[0] = g[0];
    }
  }
}

// ---------------- psetup: V-fold rows of Bt. Bt[512+hj][d] = P[d][hj]; rows 552..639 zero ----------------
// P[d][h*5+j] = sum_e kv_w[d][512+h*64+e] * Wf[(h*64+e)*5+j]
__global__ __launch_bounds__(512) void psetup_kernel(const float* __restrict__ kvw,
                                                     const float* __restrict__ Wf,
                                                     unsigned short* __restrict__ Bt){
  int row = 512 + blockIdx.x;     // 512..639
  int d = threadIdx.x;            // 0..511
  unsigned short v = 0;
  if (row < 552){
    int hj = row - 512;
    int h = hj / 5, j = hj - h * 5;
    const float* kr = kvw + (long)d * NKV + 512 + h * 64;
    const float* wr = Wf + (long)(h * 64) * 5 + j;
    float s = 0.f;
#pragma unroll
    for (int e = 0; e < 64; ++e) s += kr[e] * wr[e * 5];
    v = (unsigned short)f2bf(s);
  }
  Bt[(long)row * 512 + d] = v;
}

// ---------------- fused: memories -> summ + chunkden + bf16 (mem+pos) ----------------
__global__ __launch_bounds__(512) void prepsum_kernel(const float* __restrict__ memories,
                                                      const float* __restrict__ pos,
                                                      const void* __restrict__ mask,
                                                      const int* __restrict__ flagp,
                                                      unsigned short* __restrict__ abf_all,
                                                      float* __restrict__ summ,
                                                      float* __restrict__ chunkden){
  int n = blockIdx.x, b = blockIdx.y;
  int t = threadIdx.x;
  unsigned short* abf = abf_all ? abf_all + (long)b * MPAD * 512 : nullptr;
  if (n == NCHUNK){
    if (abf){
      for (int idx = t; idx < 96 * 128; idx += 512){
        ushort4 z = {0, 0, 0, 0};
        *(ushort4*)(abf + (long)(NMEM + (idx >> 7)) * 512 + (long)(idx & 127) * 4) = z;
      }
    }
    return;
  }
  long mbase = (long)b * NMEM + (long)n * CHUNK;
  int flag = *flagp;
  bool mybit = mask_at(mask, flag, mbase + (t & 31));
  unsigned long long bal = __ballot(mybit);
  unsigned int m32 = (unsigned int)bal;
  float den = (float)__popc(m32);
  int c4 = t & 127;
  int rh = t >> 7;               // 0..3
  const float* base = memories + mbase * HID;
  float4 v[8], p4[8];
#pragma unroll
  for (int j = 0; j < 8; ++j)
    v[j] = *(const float4*)(base + (long)(rh + 4 * j) * HID + c4 * 4);
#pragma unroll
  for (int j = 0; j < 8; ++j)
    p4[j] = *(const float4*)(pos + (rh + 4 * j) * HID + c4 * 4);
  if (abf){
#pragma unroll
    for (int j = 0; j < 8; ++j){
      ushort4 o;
      o.x = (unsigned short)f2bf(v[j].x + p4[j].x);
      o.y = (unsigned short)f2bf(v[j].y + p4[j].y);
      o.z = (unsigned short)f2bf(v[j].z + p4[j].z);
      o.w = (unsigned short)f2bf(v[j].w + p4[j].w);
      *(ushort4*)(abf + (long)(n * CHUNK + rh + 4 * j) * 512 + c4 * 4) = o;
    }
  }
  float4 acc = {0.f, 0.f, 0.f, 0.f};
#pragma unroll
  for (int j = 0; j < 8; ++j){
    if (m32 & (1u << (rh + 4 * j))){
      acc.x += v[j].x; acc.y += v[j].y; acc.z += v[j].z; acc.w += v[j].w;
    }
  }
  __shared__ float4 red[512];
  red[t] = acc;
  __syncthreads();
  if (rh == 0){
    float4 a0 = red[t], a1 = red[t + 128], a2 = red[t + 256], a3 = red[t + 384];
    float dv = den + 1e-5f;
    float4 s4;
    s4.x = (a0.x + a1.x + a2.x + a3.x) / dv;
    s4.y = (a0.y + a1.y + a2.y + a3.y) / dv;
    s4.z = (a0.z + a1.z + a2.z + a3.z) / dv;
    s4.w = (a0.w + a1.w + a2.w + a3.w) / dv;
    *(float4*)(summ + ((long)b * NCHUNK + n) * 512 + c4 * 4) = s4;
    if (t == 0) chunkden[b * NCHUNK + n] = den;
  }
}

// ---------------- prep (fallback): (mem+pos) -> bf16 A[MPAD][512] ----------------
__global__ __launch_bounds__(256) void prep_kernel(const float* __restrict__ mem,
                                                   const float* __restrict__ pos,
                                                   unsigned short* __restrict__ Abf){
  long idx = (long)blockIdx.x * 256 + threadIdx.x;
  int r = (int)(idx >> 7);
  int cv = (int)(idx & 127) << 2;
  ushort4 o;
  if (r < NMEM){
    float4 m4 = *(const float4*)(mem + (long)r * 512 + cv);
    float4 p4 = *(const float4*)(pos + (r & 31) * 512 + cv);
    o.x = (unsigned short)f2bf(m4.x + p4.x);
    o.y = (unsigned short)f2bf(m4.y + p4.y);
    o.z = (unsigned short)f2bf(m4.z + p4.z);
    o.w = (unsigned short)f2bf(m4.w + p4.w);
  } else {
    o.x = o.y = o.z = o.w = 0;
  }
  *(ushort4*)(Abf + idx * 4) = o;
}

// ---------------- generic f32 NN GEMM: C = A[M][K] @ B[K][N] * scale ----------------
__global__ __launch_bounds__(256) void gemm_nn(const float* __restrict__ A, int lda,
                                               const float* __restrict__ B, int ldb,
                                               float* __restrict__ C, int ldc,
                                               int K, float scale){
  int tid = threadIdx.x;
  int lane = tid & 63, w = tid >> 6;
  int r0 = blockIdx.x * 16 + w * 4;
  int n  = blockIdx.y * 64 + lane;
  const float* a0 = A + (long)r0 * lda;
  const float* bp = B + n;
  float acc0 = 0.f, acc1 = 0.f, acc2 = 0.f, acc3 = 0.f;
#pragma unroll 2
  for (int k = 0; k < K; k += 4){
    float b0 = bp[(long)k * ldb];
    float b1 = bp[(long)(k + 1) * ldb];
    float b2 = bp[(long)(k + 2) * ldb];
    float b3 = bp[(long)(k + 3) * ldb];
    float4 a;
    a = *(const float4*)(a0 + k);
    acc0 += a.x * b0 + a.y * b1 + a.z * b2 + a.w * b3;
    a = *(const float4*)(a0 + lda + k);
    acc1 += a.x * b0 + a.y * b1 + a.z * b2 + a.w * b3;
    a = *(const float4*)(a0 + 2 * lda + k);
    acc2 += a.x * b0 + a.y * b1 + a.z * b2 + a.w * b3;
    a = *(const float4*)(a0 + 3 * lda + k);
    acc3 += a.x * b0 + a.y * b1 + a.z * b2 + a.w * b3;
  }
  C[(long)r0 * ldc + n]       = acc0 * scale;
  C[(long)(r0 + 1) * ldc + n] = acc1 * scale;
  C[(long)(r0 + 2) * ldc + n] = acc2 * scale;
  C[(long)(r0 + 3) * ldc + n] = acc3 * scale;
}

// ---------------- uq: u_ext = queries@W2buf (y<9) and qh = queries@q_w*0.125 (y>=9) ----------------
__global__ __launch_bounds__(256) void uq_kernel(const float* __restrict__ queries,
                                                 const float* __restrict__ W2buf,
                                                 const float* __restrict__ q_w,
                                                 float* __restrict__ u_ext,
                                                 float* __restrict__ qh){
  int y = blockIdx.y;
  const float* B; int ldb; float* C; int ldc; int nbase; float scale;
  if (y < 9){ B = W2buf; ldb = W2LD; C = u_ext; ldc = W2LD; nbase = y * 64; scale = 1.0f; }
  else      { B = q_w;   ldb = 512;  C = qh;    ldc = 512;  nbase = (y - 9) * 64; scale = 0.125f; }
  int tid = threadIdx.x;
  int lane = tid & 63, w = tid >> 6;
  int r0 = blockIdx.x * 8 + w * 2;
  int n  = nbase + lane;
  const float* a0 = queries + (long)r0 * 512;
  const float* bp = B + n;
  float acc0 = 0.f, acc1 = 0.f;
#pragma unroll 4
  for (int k = 0; k < 512; k += 4){
    float b0 = bp[(long)k * ldb];
    float b1 = bp[(long)(k + 1) * ldb];
    float b2 = bp[(long)(k + 2) * ldb];
    float b3 = bp[(long)(k + 3) * ldb];
    float4 a;
    a = *(const float4*)(a0 + k);
    acc0 += a.x * b0 + a.y * b1 + a.z * b2 + a.w * b3;
    a = *(const float4*)(a0 + 512 + k);
    acc1 += a.x * b0 + a.y * b1 + a.z * b2 + a.w * b3;
  }
  C[(long)r0 * ldc + n]       = acc0 * scale;
  C[(long)(r0 + 1) * ldc + n] = acc1 * scale;
}

// ---------------- stbeta: tiled summText transpose + extra rows + betag ----------------
__global__ __launch_bounds__(256) void stbeta_kernel(const float* __restrict__ summ,
                                                     const float* __restrict__ v2,
                                                     const float* __restrict__ gbuf,
                                                     float* __restrict__ summText,
                                                     float* __restrict__ betag){
  int blk = blockIdx.x;
  int t = threadIdx.x;
  if (blk < 320){
    __shared__ float tile[64][65];
    int b = blk / 80; int rem = blk % 80;
    int n0 = (rem / 8) * 64, e0 = (rem % 8) * 64;
    int c = t & 63, rbase = t >> 6;
#pragma unroll
    for (int j = 0; j < 16; ++j){
      int r = rbase + j * 4;       // n-offset
      int n = n0 + r;
      tile[r][c] = (n < NCHUNK) ? summ[((long)b * NCHUNK + n) * 512 + e0 + c] : 0.f;
    }
    __syncthreads();
#pragma unroll
    for (int j = 0; j < 16; ++j){
      int re = rbase + j * 4;      // e-offset
      summText[(long)b * STROWS * LGLD + (long)(e0 + re) * LGLD + n0 + c] = tile[c][re];
    }
  } else if (blk < 324){
    int b = blk - 320;
    for (int idx = t; idx < 8 * LGLD; idx += 256){
      int e = idx / LGLD, n = idx - e * LGLD;
      summText[(long)b * STROWS * LGLD + (long)(512 + e) * LGLD + n] = (e == 0) ? 1.f : 0.f;
    }
  } else {
    int bb = blk - 324;            // 0..624
    int w = t >> 6, lane = t & 63;
    int row = bb * 4 + w;          // 0..2499
    const float* r = summ + (long)row * 512;
    float s = 0.f;
#pragma unroll
    for (int c = 0; c < 8; ++c) s += r[lane + 64 * c] * v2[lane + 64 * c];
    for (int d = 32; d >= 1; d >>= 1) s += __shfl_xor(s, d, 64);
    if (lane == 0){
      int b = row / NCHUNK, n = row % NCHUNK;
      betag[b * LGLD + n] = s + gbuf[0];
    }
  }
}

// ---------------- logits (NN form): 2 rows/wave, grid (16,10,NB) ----------------
__global__ __launch_bounds__(256) void logits_nn(const float* __restrict__ u_ext,
                                                 const float* __restrict__ summText,
                                                 const float* __restrict__ betag,
                                                 const float* __restrict__ chunkden,
                                                 float* __restrict__ logits){
  int b = blockIdx.z;
  int tid = threadIdx.x;
  int lane = tid & 63, w = tid >> 6;
  int r0 = blockIdx.x * 8 + w * 2;       // i
  int n  = blockIdx.y * 64 + lane;
  const float* a0 = u_ext + ((long)b * QN + r0) * W2LD;
  const float* bp = summText + (long)b * STROWS * LGLD + n;
  float acc0 = 0.f, acc1 = 0.f;
#pragma unroll 4
  for (int k = 0; k < STROWS; k += 4){
    float b0 = bp[(long)k * LGLD];
    float b1 = bp[(long)(k + 1) * LGLD];
    float b2 = bp[(long)(k + 2) * LGLD];
    float b3 = bp[(long)(k + 3) * LGLD];
    float4 a;
    a = *(const float4*)(a0 + k);
    acc0 += a.x * b0 + a.y * b1 + a.z * b2 + a.w * b3;
    a = *(const float4*)(a0 + W2LD + k);
    acc1 += a.x * b0 + a.y * b1 + a.z * b2 + a.w * b3;
  }
  if (n < NCHUNK){
    float bet = betag[b * LGLD + n];
    bool dead = (chunkden[b * NCHUNK + n] <= 0.f);
    float v0 = (acc0 + bet) * LOGIT_SCALE;
    float v1 = (acc1 + bet) * LOGIT_SCALE;
    if (dead){ v0 = v1 = -FLT_MAX; }
    long base = ((long)b * QN + r0) * LGLD + n;
    logits[base]        = v0;
    logits[base + LGLD] = v1;
  }
}

// ---------------- top-8 + softmax weights, 4 waves per (b,i) row ----------------
__global__ __launch_bounds__(256) void topk_kernel(const float* __restrict__ logits,
                                                   int* __restrict__ topi_out,
                                                   float* __restrict__ wts_out){
  int row = blockIdx.x;   // b*128+i
  __shared__ float lds[NCHUNK];
  __shared__ float wv[4];
  __shared__ int   wi[4];
  __shared__ float topv[TOPKK];
  __shared__ int   topi[TOPKK];
  int t = threadIdx.x;
  int lane = t & 63, w = t >> 6;
  for (int idx = t; idx < NCHUNK; idx += 256) lds[idx] = logits[(long)row * LGLD + idx];
  __syncthreads();
  for (int it = 0; it < TOPKK; ++it){
    float bv = -INFINITY; int bi = 0x7fffffff;
    for (int idx = t; idx < NCHUNK; idx += 256){
      float v = lds[idx];
      if (v > bv){ bv = v; bi = idx; }
    }
    for (int d = 32; d >= 1; d >>= 1){
      float ov = __shfl_xor(bv, d, 64);
      int   oi = __shfl_xor(bi, d, 64);
      if (ov > bv || (ov == bv && oi < bi)){ bv = ov; bi = oi; }
    }
    if (lane == 0){ wv[w] = bv; wi[w] = bi; }
    __syncthreads();
    if (t == 0){
      float fb = wv[0]; int fi = wi[0];
      for (int j = 1; j < 4; ++j){
        if (wv[j] > fb || (wv[j] == fb && wi[j] < fi)){ fb = wv[j]; fi = wi[j]; }
      }
      topv[it] = fb; topi[it] = fi; lds[fi] = -INFINITY;
    }
    __syncthreads();
  }
  if (t == 0){
    float m = topv[0];
    for (int r = 1; r < TOPKK; ++r) m = fmaxf(m, topv[r]);
    float e[TOPKK], s = 0.f;
    for (int r = 0; r < TOPKK; ++r){ e[r] = expf(topv[r] - m); s += e[r]; }
    for (int r = 0; r < TOPKK; ++r){
      wts_out[(long)row * TOPKK + r] = e[r] / s;
      topi_out[(long)row * TOPKK + r] = topi[r];
    }
  }
}

// ---------------- KV GEMM (K cols + folded-G cols), dbuf, XCD-aware remap, multi-batch ----------------
// Output N = 640 (512 K + 40 G + pad). 5 n-blocks per panel.
// Remap: grp=L/40, panel=grp*8+(L&7), nb=(L>>3)%5 => XCD(L%8)==panel%8.
__global__ __launch_bounds__(256) void kv_gemm(const unsigned short* __restrict__ A_all,
                                               const unsigned short* __restrict__ Bt,
                                               unsigned short* __restrict__ kv_all,
                                               int npanels){
  int L = blockIdx.x;
  int grp = L / 40;
  int within = L - grp * 40;
  int panel = grp * 8 + (within & 7);
  int nb = within >> 3;               // 0..4
  if (panel >= npanels) return;
  int bb = panel / 157;
  int p  = panel - bb * 157;
  const unsigned short* A = A_all + (size_t)bb * MPAD * 512;
  unsigned short* kvout   = kv_all + (size_t)bb * MPAD * KVLD;

  __shared__ unsigned short As[2][128 * 32];
  __shared__ unsigned short Bs[2][128 * 32];
  int m0 = p << 7, n0 = nb << 7;
  int tid = threadIdx.x;
  int wid = tid >> 6, lane = tid & 63;
  int wr = wid >> 1, wc = wid & 1;
  int lr = lane & 15, lg = lane >> 4;

  int srow = wid * 16 + (lane >> 2);
  int scol = (lane & 3) << 3;
  const unsigned short* gA0 = A  + (long)(m0 + srow) * 512 + scol;
  const unsigned short* gA1 = gA0 + 64 * 512;
  const unsigned short* gB0 = Bt + (long)(n0 + srow) * 512 + scol;
  const unsigned short* gB1 = gB0 + 64 * 512;
  int lofs0 = (wid * 16) * 32;
  int lofs1 = (64 + wid * 16) * 32;

  f32x4 acc[4][4];
#pragma unroll
  for (int i = 0; i < 4; ++i)
#pragma unroll
    for (int j = 0; j < 4; ++j) acc[i][j] = (f32x4)0.f;

#define STAGE(B, K0) { gload16(gA0 + (K0), &As[B][lofs0]); gload16(gA1 + (K0), &As[B][lofs1]); \
                       gload16(gB0 + (K0), &Bs[B][lofs0]); gload16(gB1 + (K0), &Bs[B][lofs1]); }
#define COMPUTE(B) { bf16x8 af[4], bfv[4]; \
  _Pragma("unroll") for (int mi = 0; mi < 4; ++mi) af[mi]  = *(const bf16x8*)&As[B][(wr * 64 + mi * 16 + lr) * 32 + lg * 8]; \
  _Pragma("unroll") for (int ni = 0; ni < 4; ++ni) bfv[ni] = *(const bf16x8*)&Bs[B][(wc * 64 + ni * 16 + lr) * 32 + lg * 8]; \
  _Pragma("unroll") for (int mi = 0; mi < 4; ++mi) \
    _Pragma("unroll") for (int ni = 0; ni < 4; ++ni) \
      acc[mi][ni] = __builtin_amdgcn_mfma_f32_16x16x32_bf16(af[mi], bfv[ni], acc[mi][ni], 0, 0, 0); }

  STAGE(0, 0);
  __syncthreads();
#pragma unroll 1
  for (int t = 0; t < 16; t += 2){
    if (t + 1 < 16) STAGE(1, (t + 1) * 32);
    COMPUTE(0);
    __syncthreads();
    if (t + 2 < 16) STAGE(0, (t + 2) * 32);
    COMPUTE(1);
    __syncthreads();
  }
#undef STAGE
#undef COMPUTE

#pragma unroll
  for (int mi = 0; mi < 4; ++mi)
#pragma unroll
    for (int ni = 0; ni < 4; ++ni)
#pragma unroll
      for (int rr = 0; rr < 4; ++rr){
        int gr = m0 + wr * 64 + mi * 16 + lg * 4 + rr;
        int gn = n0 + wc * 64 + ni * 16 + lr;
        kvout[(long)gr * KVLD + gn] = (unsigned short)f2bf(acc[mi][ni][rr]);
      }
}

// ---------------- attention with folded V: out_ik[0:5] directly ----------------
__global__ __launch_bounds__(256) void attn5_kernel(const float* __restrict__ qh,
                                                    const unsigned short* __restrict__ kv,
                                                    const int* __restrict__ topidx,
                                                    const float* __restrict__ wts,
                                                    const void* __restrict__ mask,
                                                    const int* __restrict__ flagp,
                                                    float* __restrict__ osc5,
                                                    int bb_arg){
  int bx = blockIdx.x;
  int bb, rem;
  const unsigned short* kvb;
  if (bb_arg < 0){
    bb = bx >> 10; rem = bx & 1023;
    kvb = kv + (size_t)bb * MPAD * KVLD;
  } else {
    bb = bb_arg; rem = bx;
    kvb = kv;
  }
  int i = rem >> 3, k = rem & 7;
  int t = threadIdx.x;
  __shared__ float qs[HID];
  __shared__ float red[4][5];
  int flag = *flagp;
  long sel = ((long)(bb * QN + i)) * TOPKK + k;
  int chunk = topidx[sel];
  float w8 = wts[sel];
  const float* qrow = qh + ((long)(bb * QN + i)) * HID;
  qs[t] = qrow[t]; qs[t + 256] = qrow[t + 256];
  __syncthreads();
  int h = t >> 5, c = t & 31;
  const unsigned short* row = kvb + (long)(chunk * CHUNK + c) * KVLD;
  const unsigned short* krow = row + h * DHEAD;
  float s = 0.f;
#pragma unroll
  for (int e8 = 0; e8 < 8; ++e8){
    bf16x8 k8 = *(const bf16x8*)(krow + e8 * 8);
#pragma unroll
    for (int j = 0; j < 8; ++j) s += qs[h * DHEAD + e8 * 8 + j] * bf2f((unsigned short)k8[j]);
  }
  bool mv = mask_at(mask, flag, (long)bb * NMEM + (long)chunk * CHUNK + c);
  if (!mv) s = -FLT_MAX;
  float m = s;
  for (int d = 16; d >= 1; d >>= 1) m = fmaxf(m, __shfl_xor(m, d, 32));
  float p = expf(s - m);
  float su = p;
  for (int d = 16; d >= 1; d >>= 1) su += __shfl_xor(su, d, 32);
  float att = p / su;
  // folded V: G[c][h][j] at row cols 512 + h*5 + j
  const unsigned short* grow = row + 512 + h * 5;
  float p0 = att * bf2f(grow[0]);
  float p1 = att * bf2f(grow[1]);
  float p2 = att * bf2f(grow[2]);
  float p3 = att * bf2f(grow[3]);
  float p4 = att * bf2f(grow[4]);
#pragma unroll
  for (int d = 32; d >= 1; d >>= 1){
    p0 += __shfl_xor(p0, d, 64);
    p1 += __shfl_xor(p1, d, 64);
    p2 += __shfl_xor(p2, d, 64);
    p3 += __shfl_xor(p3, d, 64);
    p4 += __shfl_xor(p4, d, 64);
  }
  int w = t >> 6, lane = t & 63;
  if (lane == 0){
    red[w][0] = p0; red[w][1] = p1; red[w][2] = p2; red[w][3] = p3; red[w][4] = p4;
  }
  __syncthreads();
  if (t < 5){
    float tot = red[0][t] + red[1][t] + red[2][t] + red[3][t];
    osc5[sel * 8 + t] = w8 * tot;
  }
}

// ---------------- final5: out[bi][j] = bfold[j] + sum_k osc5 ----------------
__global__ __launch_bounds__(64) void final5_kernel(const float* __restrict__ osc5,
                                                    const float* __restrict__ bfold,
                                                    float* __restrict__ out){
  int bi = blockIdx.x;   // b*128+i
  int t = threadIdx.x;
  if (t < 5){
    float a = bfold[t];
#pragma unroll
    for (int k = 0; k < TOPKK; ++k) a += osc5[((long)bi * TOPKK + k) * 8 + t];
    out[bi * 5 + t] = a;
  }
}

extern "C" void kernel_launch(void* const* d_in, const int* in_sizes, int n_in,
                              void* d_out, int out_size, void* d_ws, size_t ws_size,
                              hipStream_t stream) {
  const float* queries  = (const float*)d_in[1];
  const float* memories = (const float*)d_in[2];
  const void*  mask     = d_in[3];
  const float* sq_w = (const float*)d_in[10];
  const float* sq_b = (const float*)d_in[11];
  const float* sk_w = (const float*)d_in[12];
  const float* sk_b = (const float*)d_in[13];
  const float* q_w  = (const float*)d_in[14];
  const float* kv_w = (const float*)d_in[15];
  const float* out_w = (const float*)d_in[16];
  const float* out_b = (const float*)d_in[17];
  const float* fc2_w = (const float*)d_in[18];
  const float* fc2_b = (const float*)d_in[19];
  float* out = (float*)d_out;

  char* ws = (char*)d_ws;
  size_t o_sum  = 0;                        // 5,120,000
  size_t o_den  = o_sum + 5120000;          // 10,240
  size_t o_pos  = o_den + 10240;            // 65,536
  size_t o_wf   = o_pos + 65536;            // 10,240
  size_t o_bf   = o_wf  + 10240;            // 512
  size_t o_ti   = o_bf  + 512;              // 16,384
  size_t o_wt   = o_ti  + 16384;            // 16,384
  size_t o_flag = o_wt  + 16384;            // 512
  size_t o_qh   = o_flag + 512;             // 1,048,576
  size_t o_w2   = o_qh  + 1048576;          // 1,179,648
  size_t o_uex  = o_w2  + 1179648;          // 1,179,648
  size_t o_st   = o_uex + 1179648;          // 5,324,800
  size_t o_bg   = o_st  + 5324800;          // 10,240
  size_t o_v2   = o_bg  + 10240;            // 2,048
  size_t o_gm   = o_v2  + 2048;             // 512
  size_t o_lg   = o_gm  + 512;              // 1,310,720
  size_t o_osc5 = o_lg  + 1310720;          // 131,072
  size_t o_skt  = o_osc5 + 131072;          // 1,048,576
  size_t o_abf  = o_skt + 1048576;

  const size_t ABF_ONE = (size_t)MPAD * 512 * 2;          // 20,578,304
  const size_t ABF_ALL = ABF_ONE * NB;                    // 82,313,216
  const size_t BTW_SZ  = (size_t)KVLD * 512 * 2;          // 655,360
  const size_t KV_ONE  = (size_t)MPAD * KVLD * 2;         // 25,722,880
  size_t need_fused   = o_abf + ABF_ALL + BTW_SZ + KV_ONE;
  size_t need_batched = o_abf + ABF_ALL + BTW_SZ + KV_ONE * NB;
  bool fused   = (ws_size >= need_fused);
  bool batched = (ws_size >= need_batched);
  size_t abf_bytes = fused ? ABF_ALL : ABF_ONE;
  size_t o_btw = o_abf + abf_bytes;
  size_t o_kv  = o_btw + BTW_SZ;

  float* summ  = (float*)(ws + o_sum);
  float* den   = (float*)(ws + o_den);
  float* pos   = (float*)(ws + o_pos);
  float* Wf    = (float*)(ws + o_wf);
  float* bfold = (float*)(ws + o_bf);
  int*   ti    = (int*)  (ws + o_ti);
  float* wt    = (float*)(ws + o_wt);
  int*   flagp = (int*)  (ws + o_flag);
  float* qh    = (float*)(ws + o_qh);
  float* W2buf = (float*)(ws + o_w2);
  float* u_ext = (float*)(ws + o_uex);
  float* summText = (float*)(ws + o_st);
  float* betag = (float*)(ws + o_bg);
  float* v2    = (float*)(ws + o_v2);
  float* gbuf  = (float*)(ws + o_gm);
  float* logit = (float*)(ws + o_lg);
  float* osc5  = (float*)(ws + o_osc5);
  float* skwT  = (float*)(ws + o_skt);
  unsigned short* abf   = (unsigned short*)(ws + o_abf);
  unsigned short* btw   = (unsigned short*)(ws + o_btw);
  unsigned short* kvbuf = (unsigned short*)(ws + o_kv);

  setup_kernel<<<dim3(207), dim3(256), 0, stream>>>(
      kv_w, sk_w, mask, out_w, out_b, fc2_w, fc2_b, sq_w, sq_b, sk_b,
      btw, skwT, pos, flagp, Wf, bfold, W2buf, v2, gbuf);
  psetup_kernel<<<dim3(128), dim3(512), 0, stream>>>(kv_w, Wf, btw);

  prepsum_kernel<<<dim3(NCHUNK + 1, NB), dim3(512), 0, stream>>>(
      memories, pos, mask, flagp, fused ? abf : nullptr, summ, den);

  if (batched){
    // K + folded-G projection for all batches, right after prepsum (abf L2/L3-hot)
    int npanels = NB * 157;
    kv_gemm<<<dim3(((npanels + 7) / 8) * 40), dim3(256), 0, stream>>>(abf, btw, kvbuf, npanels);
  }

  // selection path (f32-exact)
  gemm_nn<<<dim3(32, 8), dim3(256), 0, stream>>>(sq_w, 512, skwT, 512, W2buf, W2LD, 512, 1.0f);
  uq_kernel<<<dim3(64, 17), dim3(256), 0, stream>>>(queries, W2buf, q_w, u_ext, qh);
  stbeta_kernel<<<dim3(949), dim3(256), 0, stream>>>(summ, v2, gbuf, summText, betag);
  logits_nn<<<dim3(16, 10, NB), dim3(256), 0, stream>>>(u_ext, summText, betag, den, logit);
  topk_kernel<<<dim3(NB * QN), dim3(256), 0, stream>>>(logit, ti, wt);

  if (batched){
    attn5_kernel<<<dim3(NB * QN * TOPKK), dim3(256), 0, stream>>>(
        qh, kvbuf, ti, wt, mask, flagp, osc5, -1);
  } else {
    for (int bb = 0; bb < NB; ++bb){
      const unsigned short* Ab;
      if (fused){
        Ab = abf + (size_t)bb * MPAD * 512;
      } else {
        prep_kernel<<<dim3(10048), dim3(256), 0, stream>>>(memories + (long)bb * NMEM * HID, pos, abf);
        Ab = abf;
      }
      kv_gemm<<<dim3(((157 + 7) / 8) * 40), dim3(256), 0, stream>>>(Ab, btw, kvbuf, 157);
      attn5_kernel<<<dim3(QN * TOPKK), dim3(256), 0, stream>>>(
          qh, kvbuf, ti, wt, mask, flagp, osc5, bb);
    }
  }
  final5_kernel<<<dim3(NB * QN), dim3(64), 0, stream>>>(osc5, bfold, out);
}

// Round 10
// 369.062 us; speedup vs baseline: 1.2401x; 1.0313x over previous
//
#include <hip/hip_runtime.h>
#include <hip/hip_bf16.h>
#include <float.h>
#include <math.h>

// Problem constants
#define NB      4
#define QN      128
#define HID     512
#define NMEM    20000
#define MPAD    20096    // 157*128
#define NCHUNK  625
#define CHUNK   32
#define HEADS   8
#define DHEAD   64
#define TOPKK   8
#define NKV     1024
#define GLD     64       // G buffer ld (40 used cols)
#define LOGIT_SCALE 0.044194173824159216f  // 512^-0.5
#define W2LD    576
#define STROWS  520
#define LGLD    640
#define TLD     4096     // T ld: 8 heads x 512

typedef __attribute__((ext_vector_type(8))) short bf16x8;
typedef __attribute__((ext_vector_type(4))) short bf16x4;
typedef __attribute__((ext_vector_type(4))) float f32x4;

__device__ __forceinline__ short f2bf(float f){
  __hip_bfloat16 h = __float2bfloat16(f);
  return *reinterpret_cast<short*>(&h);
}
__device__ __forceinline__ float bf2f(unsigned short s){
  __hip_bfloat16 h;
  *reinterpret_cast<unsigned short*>(&h) = s;
  return __bfloat162float(h);
}
__device__ __forceinline__ bool mask_at(const void* m, int flag, long i){
  return flag ? (((const unsigned char*)m)[i] != 0)
              : (((const int*)m)[i] != 0);
}
__device__ __forceinline__ void gload16(const void* g, void* l){
  __builtin_amdgcn_global_load_lds((const __attribute__((address_space(1))) void*)g,
                                   (__attribute__((address_space(3))) void*)l, 16, 0, 0);
}

// ---------------- setup: skwt transpose + misc + fold + vker ----------------
// grid 143: [0,64) skwt tiles; [64,128) pos/flag; [128,138) fold; [138,143) vker
__global__ __launch_bounds__(256) void setup_kernel(const float* __restrict__ skw,
                                                    const void* __restrict__ mask,
                                                    const float* __restrict__ out_w,
                                                    const float* __restrict__ out_b,
                                                    const float* __restrict__ fc2_w,
                                                    const float* __restrict__ fc2_b,
                                                    const float* __restrict__ sq_w,
                                                    const float* __restrict__ sq_b,
                                                    const float* __restrict__ sk_b,
                                                    float* __restrict__ skwT,
                                                    float* __restrict__ pos,
                                                    int* __restrict__ flagp,
                                                    float* __restrict__ Wf,
                                                    float* __restrict__ bfold,
                                                    float* __restrict__ W2buf,
                                                    float* __restrict__ v2,
                                                    float* __restrict__ gbuf){
  __shared__ float tile[64][65];
  int sub = blockIdx.x;
  int t = threadIdx.x;
  int c = t & 63, rbase = t >> 6;
  if (sub < 64){
    int e0 = (sub >> 3) * 64, j0 = (sub & 7) * 64;
#pragma unroll
    for (int j = 0; j < 16; ++j){
      int r = rbase + j * 4;
      tile[r][c] = skw[(long)(e0 + r) * 512 + j0 + c];
    }
    __syncthreads();
#pragma unroll
    for (int j = 0; j < 16; ++j){
      int rj = rbase + j * 4;
      skwT[(long)(j0 + rj) * 512 + e0 + c] = tile[c][rj];
    }
  } else if (sub < 128){
    int s = sub - 64;              // 0..63
    int cc = s >> 1;               // 0..31
    int d = (s & 1) * 256 + t;     // 0..511
    int j = (d < 256) ? d : d - 256;
    float invf = expf(-((2.0f * (float)j) / 512.0f) * 9.2103403719761836f);
    float arg = (float)(31 - cc) * invf;
    pos[cc * 512 + d] = (d < 256) ? sinf(arg) : cosf(arg);
    if (s == 0 && t == 0){
      const unsigned char* mb = (const unsigned char*)mask;
      *flagp = (mb[1] != 0) ? 1 : 0;
    }
  } else if (sub < 138){
    int s = sub - 128;             // 0..9
    int j = s >> 1;                // 0..4
    int d = (s & 1) * 256 + t;
    const float4* owr = (const float4*)(out_w + (long)d * 512);
    float acc = 0.f;
    for (int k4 = 0; k4 < 128; ++k4){
      float4 a = owr[k4];
      int k = k4 * 4;
      acc += a.x * fc2_w[k * 5 + j] + a.y * fc2_w[(k + 1) * 5 + j]
           + a.z * fc2_w[(k + 2) * 5 + j] + a.w * fc2_w[(k + 3) * 5 + j];
    }
    Wf[d * 5 + j] = acc;
    if (d == 0){
      float sb = 0.f;
      for (int k = 0; k < 512; ++k) sb += out_b[k] * fc2_w[k * 5 + j];
      bfold[j] = sb + fc2_b[j];
    }
  } else {
    int s = sub - 138;             // 0..4
    if (s < 2){
      int d = s * 256 + t;
      float acc = 0.f;
      for (int j = 0; j < 512; ++j) acc += sq_w[(long)d * 512 + j] * sk_b[j];
      W2buf[(long)d * W2LD + 512] = acc;
      for (int cc = 513; cc < W2LD; ++cc) W2buf[(long)d * W2LD + cc] = 0.f;
    } else if (s < 4){
      int e = (s - 2) * 256 + t;
      float acc = 0.f;
      for (int j = 0; j < 512; ++j) acc += skw[(long)e * 512 + j] * sq_b[j];
      v2[e] = acc;
    } else {
      __shared__ float g[256];
      g[t] = sq_b[t] * sk_b[t] + sq_b[t + 256] * sk_b[t + 256];
      __syncthreads();
      for (int d = 128; d >= 1; d >>= 1){
        if (t < d) g[t] += g[t + d];
        __syncthreads();
      }
      if (t == 0) gbuf[0] = g[0];
    }
  }
}

// ---------------- psetup: PB[64][512]: rows 0..39 = P (V-fold), rest zero ----------------
__global__ __launch_bounds__(512) void psetup_kernel(const float* __restrict__ kvw,
                                                     const float* __restrict__ Wf,
                                                     unsigned short* __restrict__ PB){
  int row = blockIdx.x;           // 0..63
  int d = threadIdx.x;            // 0..511
  unsigned short v = 0;
  if (row < 40){
    int h = row / 5, j = row - h * 5;
    const float* kr = kvw + (long)d * NKV + 512 + h * 64;
    const float* wr = Wf + (long)(h * 64) * 5 + j;
    float s = 0.f;
#pragma unroll
    for (int e = 0; e < 64; ++e) s += kr[e] * wr[e * 5];
    v = (unsigned short)f2bf(s);
  }
  PB[(long)row * 512 + d] = v;
}

// ---------------- wqk: W_qk[h*512+d'][d] = 0.125 * sum_e kv_w[d'][h*64+e]*q_w[d][h*64+e] ----------------
// grid 256 = h(8) x dp(8: 64-d' tiles) x dd(4: 128-d tiles)
__global__ __launch_bounds__(256) void wqk_kernel(const float* __restrict__ q_w,
                                                  const float* __restrict__ kvw,
                                                  unsigned short* __restrict__ wqk){
  int bx = blockIdx.x;
  int h = bx >> 5, rem2 = bx & 31, dp = rem2 >> 2, dd = rem2 & 3;
  int dpr0 = dp * 64, dd0 = dd * 128;
  __shared__ float Akv[64][65];
  __shared__ float Bq[128][65];
  int t = threadIdx.x;
  for (int idx = t; idx < 64 * 64; idx += 256){
    int r = idx >> 6, e = idx & 63;
    Akv[r][e] = kvw[(long)(dpr0 + r) * NKV + h * 64 + e];
  }
  for (int idx = t; idx < 128 * 64; idx += 256){
    int r = idx >> 6, e = idx & 63;
    Bq[r][e] = q_w[(long)(dd0 + r) * 512 + h * 64 + e];
  }
  __syncthreads();
  int ty = t >> 4, tx = t & 15;   // ty 0..15 -> d' = ty*4+u ; tx 0..15 -> d = tx*8+v
  float acc[4][8] = {};
  for (int e = 0; e < 64; ++e){
    float a0 = Akv[ty * 4 + 0][e], a1 = Akv[ty * 4 + 1][e];
    float a2 = Akv[ty * 4 + 2][e], a3 = Akv[ty * 4 + 3][e];
    float b[8];
#pragma unroll
    for (int v = 0; v < 8; ++v) b[v] = Bq[tx * 8 + v][e];
#pragma unroll
    for (int v = 0; v < 8; ++v){
      acc[0][v] += a0 * b[v];
      acc[1][v] += a1 * b[v];
      acc[2][v] += a2 * b[v];
      acc[3][v] += a3 * b[v];
    }
  }
#pragma unroll
  for (int u = 0; u < 4; ++u)
#pragma unroll
    for (int v = 0; v < 8; ++v)
      wqk[(long)(h * 512 + dpr0 + ty * 4 + u) * 512 + dd0 + tx * 8 + v] =
          (unsigned short)f2bf(acc[u][v] * 0.125f);
}

// ---------------- qbf: queries f32 -> bf16 ----------------
__global__ __launch_bounds__(256) void qbf_kernel(const float* __restrict__ queries,
                                                  unsigned short* __restrict__ qb){
  long idx = (long)blockIdx.x * 256 + threadIdx.x;   // 65536 threads x 4 elems
  float4 v = *(const float4*)(queries + idx * 4);
  ushort4 o;
  o.x = (unsigned short)f2bf(v.x);
  o.y = (unsigned short)f2bf(v.y);
  o.z = (unsigned short)f2bf(v.z);
  o.w = (unsigned short)f2bf(v.w);
  *(ushort4*)(qb + idx * 4) = o;
}

// ---------------- fused: memories -> summ + chunkden + bf16 (mem+pos) ----------------
__global__ __launch_bounds__(512) void prepsum_kernel(const float* __restrict__ memories,
                                                      const float* __restrict__ pos,
                                                      const void* __restrict__ mask,
                                                      const int* __restrict__ flagp,
                                                      unsigned short* __restrict__ abf_all,
                                                      float* __restrict__ summ,
                                                      float* __restrict__ chunkden){
  int n = blockIdx.x, b = blockIdx.y;
  int t = threadIdx.x;
  unsigned short* abf = abf_all + (long)b * MPAD * 512;
  if (n == NCHUNK){
    for (int idx = t; idx < 96 * 128; idx += 512){
      ushort4 z = {0, 0, 0, 0};
      *(ushort4*)(abf + (long)(NMEM + (idx >> 7)) * 512 + (long)(idx & 127) * 4) = z;
    }
    return;
  }
  long mbase = (long)b * NMEM + (long)n * CHUNK;
  int flag = *flagp;
  bool mybit = mask_at(mask, flag, mbase + (t & 31));
  unsigned long long bal = __ballot(mybit);
  unsigned int m32 = (unsigned int)bal;
  float den = (float)__popc(m32);
  int c4 = t & 127;
  int rh = t >> 7;
  const float* base = memories + mbase * HID;
  float4 v[8], p4[8];
#pragma unroll
  for (int j = 0; j < 8; ++j)
    v[j] = *(const float4*)(base + (long)(rh + 4 * j) * HID + c4 * 4);
#pragma unroll
  for (int j = 0; j < 8; ++j)
    p4[j] = *(const float4*)(pos + (rh + 4 * j) * HID + c4 * 4);
#pragma unroll
  for (int j = 0; j < 8; ++j){
    ushort4 o;
    o.x = (unsigned short)f2bf(v[j].x + p4[j].x);
    o.y = (unsigned short)f2bf(v[j].y + p4[j].y);
    o.z = (unsigned short)f2bf(v[j].z + p4[j].z);
    o.w = (unsigned short)f2bf(v[j].w + p4[j].w);
    *(ushort4*)(abf + (long)(n * CHUNK + rh + 4 * j) * 512 + c4 * 4) = o;
  }
  float4 acc = {0.f, 0.f, 0.f, 0.f};
#pragma unroll
  for (int j = 0; j < 8; ++j){
    if (m32 & (1u << (rh + 4 * j))){
      acc.x += v[j].x; acc.y += v[j].y; acc.z += v[j].z; acc.w += v[j].w;
    }
  }
  __shared__ float4 red[512];
  red[t] = acc;
  __syncthreads();
  if (rh == 0){
    float4 a0 = red[t], a1 = red[t + 128], a2 = red[t + 256], a3 = red[t + 384];
    float dv = den + 1e-5f;
    float4 s4;
    s4.x = (a0.x + a1.x + a2.x + a3.x) / dv;
    s4.y = (a0.y + a1.y + a2.y + a3.y) / dv;
    s4.z = (a0.z + a1.z + a2.z + a3.z) / dv;
    s4.w = (a0.w + a1.w + a2.w + a3.w) / dv;
    *(float4*)(summ + ((long)b * NCHUNK + n) * 512 + c4 * 4) = s4;
    if (t == 0) chunkden[b * NCHUNK + n] = den;
  }
}

// ---------------- ggemm: G = abf @ PB^T, 256 rows x 64 cols per block ----------------
__global__ __launch_bounds__(256) void ggemm(const unsigned short* __restrict__ abf_all,
                                             const unsigned short* __restrict__ PB,
                                             unsigned short* __restrict__ g_all){
  int L = blockIdx.x;
  int bb = L / 79, g = L - bb * 79;
  const unsigned short* A = abf_all + (size_t)bb * MPAD * 512;
  unsigned short* gout = g_all + (size_t)bb * MPAD * GLD;
  __shared__ unsigned short As[2][256 * 32];
  __shared__ unsigned short Bs[2][64 * 32];
  int tid = threadIdx.x, wid = tid >> 6, lane = tid & 63;
  int lr = lane & 15, lg = lane >> 4;
  int scol = (lane & 3) << 3;
  int srow = wid * 16 + (lane >> 2);      // 0..63
  long rbase = (long)g * 256 + srow;
  long ra0 = rbase;            if (ra0 > MPAD - 1) ra0 = MPAD - 1;
  long ra1 = rbase + 64;       if (ra1 > MPAD - 1) ra1 = MPAD - 1;
  long ra2 = rbase + 128;      if (ra2 > MPAD - 1) ra2 = MPAD - 1;
  long ra3 = rbase + 192;      if (ra3 > MPAD - 1) ra3 = MPAD - 1;
  const unsigned short* gA0 = A + ra0 * 512 + scol;
  const unsigned short* gA1 = A + ra1 * 512 + scol;
  const unsigned short* gA2 = A + ra2 * 512 + scol;
  const unsigned short* gA3 = A + ra3 * 512 + scol;
  const unsigned short* gB0 = PB + (long)srow * 512 + scol;
  int lA0 = (wid * 16) * 32, lA1 = (64 + wid * 16) * 32;
  int lA2 = (128 + wid * 16) * 32, lA3 = (192 + wid * 16) * 32;
  int lB0 = (wid * 16) * 32;

  f32x4 acc[4][4];
#pragma unroll
  for (int i = 0; i < 4; ++i)
#pragma unroll
    for (int j = 0; j < 4; ++j) acc[i][j] = (f32x4)0.f;

#define STAGE(B, K0) { gload16(gA0 + (K0), &As[B][lA0]); gload16(gA1 + (K0), &As[B][lA1]); \
                       gload16(gA2 + (K0), &As[B][lA2]); gload16(gA3 + (K0), &As[B][lA3]); \
                       gload16(gB0 + (K0), &Bs[B][lB0]); }
#define COMPUTE(B) { bf16x8 af[4], bfv[4]; \
  _Pragma("unroll") for (int mi = 0; mi < 4; ++mi) af[mi]  = *(const bf16x8*)&As[B][(wid * 64 + mi * 16 + lr) * 32 + lg * 8]; \
  _Pragma("unroll") for (int ni = 0; ni < 4; ++ni) bfv[ni] = *(const bf16x8*)&Bs[B][(ni * 16 + lr) * 32 + lg * 8]; \
  _Pragma("unroll") for (int mi = 0; mi < 4; ++mi) \
    _Pragma("unroll") for (int ni = 0; ni < 4; ++ni) \
      acc[mi][ni] = __builtin_amdgcn_mfma_f32_16x16x32_bf16(af[mi], bfv[ni], acc[mi][ni], 0, 0, 0); }

  STAGE(0, 0);
  __syncthreads();
#pragma unroll 1
  for (int t = 0; t < 16; t += 2){
    if (t + 1 < 16) STAGE(1, (t + 1) * 32);
    COMPUTE(0);
    __syncthreads();
    if (t + 2 < 16) STAGE(0, (t + 2) * 32);
    COMPUTE(1);
    __syncthreads();
  }
#undef STAGE
#undef COMPUTE

#pragma unroll
  for (int mi = 0; mi < 4; ++mi)
#pragma unroll
    for (int ni = 0; ni < 4; ++ni)
#pragma unroll
      for (int rr = 0; rr < 4; ++rr){
        long gr = (long)g * 256 + wid * 64 + mi * 16 + lg * 4 + rr;
        int gn = ni * 16 + lr;
        if (gr < MPAD)
          gout[gr * GLD + gn] = (unsigned short)f2bf(acc[mi][ni][rr]);
      }
}

// ---------------- tgemm: T = qbf @ wqk^T (f32 out), 128x128 tiles ----------------
__global__ __launch_bounds__(256) void tgemm(const unsigned short* __restrict__ Aq,
                                             const unsigned short* __restrict__ Bw,
                                             float* __restrict__ T){
  int L = blockIdx.x;
  int panel = L >> 5, nb = L & 31;
  int m0 = panel << 7, n0 = nb << 7;
  __shared__ unsigned short As[2][128 * 32];
  __shared__ unsigned short Bs[2][128 * 32];
  int tid = threadIdx.x, wid = tid >> 6, lane = tid & 63;
  int wr = wid >> 1, wc = wid & 1;
  int lr = lane & 15, lg = lane >> 4;
  int srow = wid * 16 + (lane >> 2);
  int scol = (lane & 3) << 3;
  const unsigned short* gA0 = Aq + (long)(m0 + srow) * 512 + scol;
  const unsigned short* gA1 = gA0 + 64 * 512;
  const unsigned short* gB0 = Bw + (long)(n0 + srow) * 512 + scol;
  const unsigned short* gB1 = gB0 + 64 * 512;
  int lofs0 = (wid * 16) * 32;
  int lofs1 = (64 + wid * 16) * 32;

  f32x4 acc[4][4];
#pragma unroll
  for (int i = 0; i < 4; ++i)
#pragma unroll
    for (int j = 0; j < 4; ++j) acc[i][j] = (f32x4)0.f;

#define STAGE(B, K0) { gload16(gA0 + (K0), &As[B][lofs0]); gload16(gA1 + (K0), &As[B][lofs1]); \
                       gload16(gB0 + (K0), &Bs[B][lofs0]); gload16(gB1 + (K0), &Bs[B][lofs1]); }
#define COMPUTE(B) { bf16x8 af[4], bfv[4]; \
  _Pragma("unroll") for (int mi = 0; mi < 4; ++mi) af[mi]  = *(const bf16x8*)&As[B][(wr * 64 + mi * 16 + lr) * 32 + lg * 8]; \
  _Pragma("unroll") for (int ni = 0; ni < 4; ++ni) bfv[ni] = *(const bf16x8*)&Bs[B][(wc * 64 + ni * 16 + lr) * 32 + lg * 8]; \
  _Pragma("unroll") for (int mi = 0; mi < 4; ++mi) \
    _Pragma("unroll") for (int ni = 0; ni < 4; ++ni) \
      acc[mi][ni] = __builtin_amdgcn_mfma_f32_16x16x32_bf16(af[mi], bfv[ni], acc[mi][ni], 0, 0, 0); }

  STAGE(0, 0);
  __syncthreads();
#pragma unroll 1
  for (int t = 0; t < 16; t += 2){
    if (t + 1 < 16) STAGE(1, (t + 1) * 32);
    COMPUTE(0);
    __syncthreads();
    if (t + 2 < 16) STAGE(0, (t + 2) * 32);
    COMPUTE(1);
    __syncthreads();
  }
#undef STAGE
#undef COMPUTE

#pragma unroll
  for (int mi = 0; mi < 4; ++mi)
#pragma unroll
    for (int ni = 0; ni < 4; ++ni)
#pragma unroll
      for (int rr = 0; rr < 4; ++rr){
        int gr = m0 + wr * 64 + mi * 16 + lg * 4 + rr;
        int gn = n0 + wc * 64 + ni * 16 + lr;
        T[(long)gr * TLD + gn] = acc[mi][ni][rr];
      }
}

// ---------------- generic f32 NN GEMM: C = A[M][K] @ B[K][N] * scale ----------------
__global__ __launch_bounds__(256) void gemm_nn(const float* __restrict__ A, int lda,
                                               const float* __restrict__ B, int ldb,
                                               float* __restrict__ C, int ldc,
                                               int K, float scale){
  int tid = threadIdx.x;
  int lane = tid & 63, w = tid >> 6;
  int r0 = blockIdx.x * 16 + w * 4;
  int n  = blockIdx.y * 64 + lane;
  const float* a0 = A + (long)r0 * lda;
  const float* bp = B + n;
  float acc0 = 0.f, acc1 = 0.f, acc2 = 0.f, acc3 = 0.f;
#pragma unroll 2
  for (int k = 0; k < K; k += 4){
    float b0 = bp[(long)k * ldb];
    float b1 = bp[(long)(k + 1) * ldb];
    float b2 = bp[(long)(k + 2) * ldb];
    float b3 = bp[(long)(k + 3) * ldb];
    float4 a;
    a = *(const float4*)(a0 + k);
    acc0 += a.x * b0 + a.y * b1 + a.z * b2 + a.w * b3;
    a = *(const float4*)(a0 + lda + k);
    acc1 += a.x * b0 + a.y * b1 + a.z * b2 + a.w * b3;
    a = *(const float4*)(a0 + 2 * lda + k);
    acc2 += a.x * b0 + a.y * b1 + a.z * b2 + a.w * b3;
    a = *(const float4*)(a0 + 3 * lda + k);
    acc3 += a.x * b0 + a.y * b1 + a.z * b2 + a.w * b3;
  }
  C[(long)r0 * ldc + n]       = acc0 * scale;
  C[(long)(r0 + 1) * ldc + n] = acc1 * scale;
  C[(long)(r0 + 2) * ldc + n] = acc2 * scale;
  C[(long)(r0 + 3) * ldc + n] = acc3 * scale;
}

// ---------------- stbeta: tiled summText transpose + extra rows + betag ----------------
__global__ __launch_bounds__(256) void stbeta_kernel(const float* __restrict__ summ,
                                                     const float* __restrict__ v2,
                                                     const float* __restrict__ gbuf,
                                                     float* __restrict__ summText,
                                                     float* __restrict__ betag){
  int blk = blockIdx.x;
  int t = threadIdx.x;
  if (blk < 320){
    __shared__ float tile[64][65];
    int b = blk / 80; int rem = blk % 80;
    int n0 = (rem / 8) * 64, e0 = (rem % 8) * 64;
    int c = t & 63, rbase = t >> 6;
#pragma unroll
    for (int j = 0; j < 16; ++j){
      int r = rbase + j * 4;
      int n = n0 + r;
      tile[r][c] = (n < NCHUNK) ? summ[((long)b * NCHUNK + n) * 512 + e0 + c] : 0.f;
    }
    __syncthreads();
#pragma unroll
    for (int j = 0; j < 16; ++j){
      int re = rbase + j * 4;
      summText[(long)b * STROWS * LGLD + (long)(e0 + re) * LGLD + n0 + c] = tile[c][re];
    }
  } else if (blk < 324){
    int b = blk - 320;
    for (int idx = t; idx < 8 * LGLD; idx += 256){
      int e = idx / LGLD, n = idx - e * LGLD;
      summText[(long)b * STROWS * LGLD + (long)(512 + e) * LGLD + n] = (e == 0) ? 1.f : 0.f;
    }
  } else {
    int bb = blk - 324;
    int w = t >> 6, lane = t & 63;
    int row = bb * 4 + w;
    const float* r = summ + (long)row * 512;
    float s = 0.f;
#pragma unroll
    for (int c = 0; c < 8; ++c) s += r[lane + 64 * c] * v2[lane + 64 * c];
    for (int d = 32; d >= 1; d >>= 1) s += __shfl_xor(s, d, 64);
    if (lane == 0){
      int b = row / NCHUNK, n = row % NCHUNK;
      betag[b * LGLD + n] = s + gbuf[0];
    }
  }
}

// ---------------- logits (NN form): 2 rows/wave, grid (16,10,NB) ----------------
__global__ __launch_bounds__(256) void logits_nn(const float* __restrict__ u_ext,
                                                 const float* __restrict__ summText,
                                                 const float* __restrict__ betag,
                                                 const float* __restrict__ chunkden,
                                                 float* __restrict__ logits){
  int b = blockIdx.z;
  int tid = threadIdx.x;
  int lane = tid & 63, w = tid >> 6;
  int r0 = blockIdx.x * 8 + w * 2;
  int n  = blockIdx.y * 64 + lane;
  const float* a0 = u_ext + ((long)b * QN + r0) * W2LD;
  const float* bp = summText + (long)b * STROWS * LGLD + n;
  float acc0 = 0.f, acc1 = 0.f;
#pragma unroll 4
  for (int k = 0; k < STROWS; k += 4){
    float b0 = bp[(long)k * LGLD];
    float b1 = bp[(long)(k + 1) * LGLD];
    float b2 = bp[(long)(k + 2) * LGLD];
    float b3 = bp[(long)(k + 3) * LGLD];
    float4 a;
    a = *(const float4*)(a0 + k);
    acc0 += a.x * b0 + a.y * b1 + a.z * b2 + a.w * b3;
    a = *(const float4*)(a0 + W2LD + k);
    acc1 += a.x * b0 + a.y * b1 + a.z * b2 + a.w * b3;
  }
  if (n < NCHUNK){
    float bet = betag[b * LGLD + n];
    bool dead = (chunkden[b * NCHUNK + n] <= 0.f);
    float v0 = (acc0 + bet) * LOGIT_SCALE;
    float v1 = (acc1 + bet) * LOGIT_SCALE;
    if (dead){ v0 = v1 = -FLT_MAX; }
    long base = ((long)b * QN + r0) * LGLD + n;
    logits[base]        = v0;
    logits[base + LGLD] = v1;
  }
}

// ---------------- top-8 + softmax weights, 4 waves per (b,i) row ----------------
__global__ __launch_bounds__(256) void topk_kernel(const float* __restrict__ logits,
                                                   int* __restrict__ topi_out,
                                                   float* __restrict__ wts_out){
  int row = blockIdx.x;
  __shared__ float lds[NCHUNK];
  __shared__ float wv[4];
  __shared__ int   wi[4];
  __shared__ float topv[TOPKK];
  __shared__ int   topi[TOPKK];
  int t = threadIdx.x;
  int lane = t & 63, w = t >> 6;
  for (int idx = t; idx < NCHUNK; idx += 256) lds[idx] = logits[(long)row * LGLD + idx];
  __syncthreads();
  for (int it = 0; it < TOPKK; ++it){
    float bv = -INFINITY; int bi = 0x7fffffff;
    for (int idx = t; idx < NCHUNK; idx += 256){
      float v = lds[idx];
      if (v > bv){ bv = v; bi = idx; }
    }
    for (int d = 32; d >= 1; d >>= 1){
      float ov = __shfl_xor(bv, d, 64);
      int   oi = __shfl_xor(bi, d, 64);
      if (ov > bv || (ov == bv && oi < bi)){ bv = ov; bi = oi; }
    }
    if (lane == 0){ wv[w] = bv; wi[w] = bi; }
    __syncthreads();
    if (t == 0){
      float fb = wv[0]; int fi = wi[0];
      for (int j = 1; j < 4; ++j){
        if (wv[j] > fb || (wv[j] == fb && wi[j] < fi)){ fb = wv[j]; fi = wi[j]; }
      }
      topv[it] = fb; topi[it] = fi; lds[fi] = -INFINITY;
    }
    __syncthreads();
  }
  if (t == 0){
    float m = topv[0];
    for (int r = 1; r < TOPKK; ++r) m = fmaxf(m, topv[r]);
    float e[TOPKK], s = 0.f;
    for (int r = 0; r < TOPKK; ++r){ e[r] = expf(topv[r] - m); s += e[r]; }
    for (int r = 0; r < TOPKK; ++r){
      wts_out[(long)row * TOPKK + r] = e[r] / s;
      topi_out[(long)row * TOPKK + r] = topi[r];
    }
  }
}

// ---------------- attention: sim from T . A (LDS-staged), G-fold output ----------------
#define ALDP 516   // A_lds row stride (bf16 elems): 2-way-free banks, 8B aligned
__global__ __launch_bounds__(256) void attn5_kernel(const float* __restrict__ T,
                                                    const unsigned short* __restrict__ abf_all,
                                                    const unsigned short* __restrict__ g_all,
                                                    const int* __restrict__ topidx,
                                                    const float* __restrict__ wts,
                                                    const void* __restrict__ mask,
                                                    const int* __restrict__ flagp,
                                                    float* __restrict__ osc5){
  int bx = blockIdx.x;
  int bb = bx >> 10, rem = bx & 1023;
  int i = rem >> 3, k = rem & 7;
  const unsigned short* abf = abf_all + (size_t)bb * MPAD * 512;
  const unsigned short* gb  = g_all + (size_t)bb * MPAD * GLD;
  int t = threadIdx.x;
  __shared__ unsigned short A_lds[32 * ALDP];
  __shared__ float T_lds[TLD];
  __shared__ float red[4][5];
  int flag = *flagp;
  long sel = ((long)(bb * QN + i)) * TOPKK + k;
  int chunk = topidx[sel];
  float w8 = wts[sel];
  // stage T row (4096 f32)
  const float* Trow = T + (long)(bb * QN + i) * TLD;
  for (int idx = t; idx < 1024; idx += 256)
    *(float4*)&T_lds[idx * 4] = *(const float4*)&Trow[idx * 4];
  // stage A rows (32 x 512 bf16)
  {
    int r = t >> 3, cb = (t & 7) * 64;
    const unsigned short* src = abf + (long)(chunk * CHUNK + r) * 512 + cb;
    unsigned short* dst = &A_lds[r * ALDP + cb];
#pragma unroll
    for (int j = 0; j < 8; ++j){
      bf16x8 a8 = *(const bf16x8*)(src + j * 8);
      bf16x4 lo = {a8[0], a8[1], a8[2], a8[3]};
      bf16x4 hi = {a8[4], a8[5], a8[6], a8[7]};
      *(bf16x4*)(dst + j * 8)     = lo;
      *(bf16x4*)(dst + j * 8 + 4) = hi;
    }
  }
  __syncthreads();
  int h = t >> 5, c = t & 31;
  const unsigned short* arow = &A_lds[c * ALDP];
  const float* tp = &T_lds[h * 512];
  float s = 0.f;
#pragma unroll 4
  for (int e8 = 0; e8 < 64; ++e8){
    bf16x4 alo = *(const bf16x4*)(arow + e8 * 8);
    bf16x4 ahi = *(const bf16x4*)(arow + e8 * 8 + 4);
    float4 ta = *(const float4*)(tp + e8 * 8);
    float4 tb = *(const float4*)(tp + e8 * 8 + 4);
    s += bf2f((unsigned short)alo[0]) * ta.x + bf2f((unsigned short)alo[1]) * ta.y
       + bf2f((unsigned short)alo[2]) * ta.z + bf2f((unsigned short)alo[3]) * ta.w
       + bf2f((unsigned short)ahi[0]) * tb.x + bf2f((unsigned short)ahi[1]) * tb.y
       + bf2f((unsigned short)ahi[2]) * tb.z + bf2f((unsigned short)ahi[3]) * tb.w;
  }
  bool mv = mask_at(mask, flag, (long)bb * NMEM + (long)chunk * CHUNK + c);
  if (!mv) s = -FLT_MAX;
  float m = s;
  for (int d = 16; d >= 1; d >>= 1) m = fmaxf(m, __shfl_xor(m, d, 32));
  float p = expf(s - m);
  float su = p;
  for (int d = 16; d >= 1; d >>= 1) su += __shfl_xor(su, d, 32);
  float att = p / su;
  const unsigned short* grow = gb + (long)(chunk * CHUNK + c) * GLD + h * 5;
  float p0 = att * bf2f(grow[0]);
  float p1 = att * bf2f(grow[1]);
  float p2 = att * bf2f(grow[2]);
  float p3 = att * bf2f(grow[3]);
  float p4 = att * bf2f(grow[4]);
#pragma unroll
  for (int d = 32; d >= 1; d >>= 1){
    p0 += __shfl_xor(p0, d, 64);
    p1 += __shfl_xor(p1, d, 64);
    p2 += __shfl_xor(p2, d, 64);
    p3 += __shfl_xor(p3, d, 64);
    p4 += __shfl_xor(p4, d, 64);
  }
  int w = t >> 6, lane = t & 63;
  if (lane == 0){
    red[w][0] = p0; red[w][1] = p1; red[w][2] = p2; red[w][3] = p3; red[w][4] = p4;
  }
  __syncthreads();
  if (t < 5){
    float tot = red[0][t] + red[1][t] + red[2][t] + red[3][t];
    osc5[sel * 8 + t] = w8 * tot;
  }
}

// ---------------- final5 ----------------
__global__ __launch_bounds__(64) void final5_kernel(const float* __restrict__ osc5,
                                                    const float* __restrict__ bfold,
                                                    float* __restrict__ out){
  int bi = blockIdx.x;
  int t = threadIdx.x;
  if (t < 5){
    float a = bfold[t];
#pragma unroll
    for (int k = 0; k < TOPKK; ++k) a += osc5[((long)bi * TOPKK + k) * 8 + t];
    out[bi * 5 + t] = a;
  }
}

extern "C" void kernel_launch(void* const* d_in, const int* in_sizes, int n_in,
                              void* d_out, int out_size, void* d_ws, size_t ws_size,
                              hipStream_t stream) {
  const float* queries  = (const float*)d_in[1];
  const float* memories = (const float*)d_in[2];
  const void*  mask     = d_in[3];
  const float* sq_w = (const float*)d_in[10];
  const float* sq_b = (const float*)d_in[11];
  const float* sk_w = (const float*)d_in[12];
  const float* sk_b = (const float*)d_in[13];
  const float* q_w  = (const float*)d_in[14];
  const float* kv_w = (const float*)d_in[15];
  const float* out_w = (const float*)d_in[16];
  const float* out_b = (const float*)d_in[17];
  const float* fc2_w = (const float*)d_in[18];
  const float* fc2_b = (const float*)d_in[19];
  float* out = (float*)d_out;

  char* ws = (char*)d_ws;
  size_t off = 0;
  auto alloc = [&](size_t bytes){ size_t o = off; off += (bytes + 511) & ~(size_t)511; return o; };
  size_t o_sum  = alloc(5120000);
  size_t o_den  = alloc(10240);
  size_t o_pos  = alloc(65536);
  size_t o_wf   = alloc(10240);
  size_t o_bf   = alloc(512);
  size_t o_ti   = alloc(16384);
  size_t o_wt   = alloc(16384);
  size_t o_flag = alloc(512);
  size_t o_w2   = alloc(1179648);
  size_t o_uex  = alloc(1179648);
  size_t o_st   = alloc(5324800);
  size_t o_bg   = alloc(10240);
  size_t o_v2   = alloc(2048);
  size_t o_gm   = alloc(512);
  size_t o_lg   = alloc(1310720);
  size_t o_osc5 = alloc(131072);
  size_t o_skt  = alloc(1048576);
  size_t o_qbf  = alloc(524288);
  size_t o_wqk  = alloc(4194304);
  size_t o_T    = alloc((size_t)NB * QN * TLD * 4);       // 8,388,608
  size_t o_pb   = alloc(65536);
  size_t o_abf  = alloc((size_t)NB * MPAD * 512 * 2);     // 82,313,216
  size_t o_g    = alloc((size_t)NB * MPAD * GLD * 2);     // 10,289,152

  float* summ  = (float*)(ws + o_sum);
  float* den   = (float*)(ws + o_den);
  float* pos   = (float*)(ws + o_pos);
  float* Wf    = (float*)(ws + o_wf);
  float* bfold = (float*)(ws + o_bf);
  int*   ti    = (int*)  (ws + o_ti);
  float* wt    = (float*)(ws + o_wt);
  int*   flagp = (int*)  (ws + o_flag);
  float* W2buf = (float*)(ws + o_w2);
  float* u_ext = (float*)(ws + o_uex);
  float* summText = (float*)(ws + o_st);
  float* betag = (float*)(ws + o_bg);
  float* v2    = (float*)(ws + o_v2);
  float* gbuf  = (float*)(ws + o_gm);
  float* logit = (float*)(ws + o_lg);
  float* osc5  = (float*)(ws + o_osc5);
  float* skwT  = (float*)(ws + o_skt);
  unsigned short* qb   = (unsigned short*)(ws + o_qbf);
  unsigned short* wqk  = (unsigned short*)(ws + o_wqk);
  float* Tbuf  = (float*)(ws + o_T);
  unsigned short* PB   = (unsigned short*)(ws + o_pb);
  unsigned short* abf  = (unsigned short*)(ws + o_abf);
  unsigned short* gall = (unsigned short*)(ws + o_g);

  setup_kernel<<<dim3(143), dim3(256), 0, stream>>>(
      sk_w, mask, out_w, out_b, fc2_w, fc2_b, sq_w, sq_b, sk_b,
      skwT, pos, flagp, Wf, bfold, W2buf, v2, gbuf);
  psetup_kernel<<<dim3(64), dim3(512), 0, stream>>>(kv_w, Wf, PB);
  wqk_kernel<<<dim3(256), dim3(256), 0, stream>>>(q_w, kv_w, wqk);
  qbf_kernel<<<dim3(256), dim3(256), 0, stream>>>(queries, qb);

  prepsum_kernel<<<dim3(NCHUNK + 1, NB), dim3(512), 0, stream>>>(
      memories, pos, mask, flagp, abf, summ, den);

  ggemm<<<dim3(79 * NB), dim3(256), 0, stream>>>(abf, PB, gall);
  tgemm<<<dim3(128), dim3(256), 0, stream>>>(qb, wqk, Tbuf);

  // selection path (f32-exact)
  gemm_nn<<<dim3(32, 8), dim3(256), 0, stream>>>(sq_w, 512, skwT, 512, W2buf, W2LD, 512, 1.0f);
  gemm_nn<<<dim3(32, 9), dim3(256), 0, stream>>>(queries, 512, W2buf, W2LD, u_ext, W2LD, 512, 1.0f);
  stbeta_kernel<<<dim3(949), dim3(256), 0, stream>>>(summ, v2, gbuf, summText, betag);
  logits_nn<<<dim3(16, 10, NB), dim3(256), 0, stream>>>(u_ext, summText, betag, den, logit);
  topk_kernel<<<dim3(NB * QN), dim3(256), 0, stream>>>(logit, ti, wt);

  attn5_kernel<<<dim3(NB * QN * TOPKK), dim3(256), 0, stream>>>(
      Tbuf, abf, gall, ti, wt, mask, flagp, osc5);
  final5_kernel<<<dim3(NB * QN), dim3(64), 0, stream>>>(osc5, bfold, out);
}

// Round 11
// 310.065 us; speedup vs baseline: 1.4761x; 1.1903x over previous
//
#include <hip/hip_runtime.h>
#include <hip/hip_bf16.h>
#include <float.h>
#include <math.h>

// Problem constants
#define NB      4
#define QN      128
#define HID     512
#define NMEM    20000
#define MPAD    20096    // 157*128
#define NCHUNK  625
#define CHUNK   32
#define HEADS   8
#define DHEAD   64
#define TOPKK   8
#define NKV     1024
#define GLD     64       // G buffer ld (40 used cols)
#define LOGIT_SCALE 0.044194173824159216f  // 512^-0.5
#define W2LD    576
#define STROWS  520
#define LGLD    640
#define TLD     4096     // T ld: 8 heads x 512

typedef __attribute__((ext_vector_type(8))) short bf16x8;
typedef __attribute__((ext_vector_type(4))) short bf16x4;
typedef __attribute__((ext_vector_type(4))) float f32x4;

__device__ __forceinline__ short f2bf(float f){
  __hip_bfloat16 h = __float2bfloat16(f);
  return *reinterpret_cast<short*>(&h);
}
__device__ __forceinline__ float bf2f(unsigned short s){
  __hip_bfloat16 h;
  *reinterpret_cast<unsigned short*>(&h) = s;
  return __bfloat162float(h);
}
__device__ __forceinline__ bool mask_at(const void* m, int flag, long i){
  return flag ? (((const unsigned char*)m)[i] != 0)
              : (((const int*)m)[i] != 0);
}
__device__ __forceinline__ void gload16(const void* g, void* l){
  __builtin_amdgcn_global_load_lds((const __attribute__((address_space(1))) void*)g,
                                   (__attribute__((address_space(3))) void*)l, 16, 0, 0);
}

// ---------------- bigsetup: skwt transpose + misc + fold + vker + wqk + qbf ----------------
// grid 655: [0,64) skwt; [64,128) pos/flag; [128,138) fold; [138,143) vker;
//           [143,399) wqk; [399,655) qbf
__global__ __launch_bounds__(256) void bigsetup_kernel(const float* __restrict__ skw,
                                                       const void* __restrict__ mask,
                                                       const float* __restrict__ out_w,
                                                       const float* __restrict__ out_b,
                                                       const float* __restrict__ fc2_w,
                                                       const float* __restrict__ fc2_b,
                                                       const float* __restrict__ sq_w,
                                                       const float* __restrict__ sq_b,
                                                       const float* __restrict__ sk_b,
                                                       const float* __restrict__ q_w,
                                                       const float* __restrict__ kvw,
                                                       const float* __restrict__ queries,
                                                       float* __restrict__ skwT,
                                                       float* __restrict__ pos,
                                                       int* __restrict__ flagp,
                                                       float* __restrict__ Wf,
                                                       float* __restrict__ bfold,
                                                       float* __restrict__ W2buf,
                                                       float* __restrict__ v2,
                                                       float* __restrict__ gbuf,
                                                       unsigned short* __restrict__ wqk,
                                                       unsigned short* __restrict__ qb){
  __shared__ float sm[12480];   // 49,920 B pool
  int sub = blockIdx.x;
  int t = threadIdx.x;
  if (sub < 64){
    float (*tile)[65] = (float(*)[65])sm;
    int c = t & 63, rbase = t >> 6;
    int e0 = (sub >> 3) * 64, j0 = (sub & 7) * 64;
#pragma unroll
    for (int j = 0; j < 16; ++j){
      int r = rbase + j * 4;
      tile[r][c] = skw[(long)(e0 + r) * 512 + j0 + c];
    }
    __syncthreads();
#pragma unroll
    for (int j = 0; j < 16; ++j){
      int rj = rbase + j * 4;
      skwT[(long)(j0 + rj) * 512 + e0 + c] = tile[c][rj];
    }
  } else if (sub < 128){
    int s = sub - 64;              // 0..63
    int cc = s >> 1;               // 0..31
    int d = (s & 1) * 256 + t;     // 0..511
    int j = (d < 256) ? d : d - 256;
    float invf = expf(-((2.0f * (float)j) / 512.0f) * 9.2103403719761836f);
    float arg = (float)(31 - cc) * invf;
    pos[cc * 512 + d] = (d < 256) ? sinf(arg) : cosf(arg);
    if (s == 0 && t == 0){
      const unsigned char* mb = (const unsigned char*)mask;
      *flagp = (mb[1] != 0) ? 1 : 0;
    }
  } else if (sub < 138){
    int s = sub - 128;             // 0..9
    int j = s >> 1;                // 0..4
    int d = (s & 1) * 256 + t;
    const float4* owr = (const float4*)(out_w + (long)d * 512);
    float acc = 0.f;
    for (int k4 = 0; k4 < 128; ++k4){
      float4 a = owr[k4];
      int k = k4 * 4;
      acc += a.x * fc2_w[k * 5 + j] + a.y * fc2_w[(k + 1) * 5 + j]
           + a.z * fc2_w[(k + 2) * 5 + j] + a.w * fc2_w[(k + 3) * 5 + j];
    }
    Wf[d * 5 + j] = acc;
    if (d == 0){
      float sb = 0.f;
      for (int k = 0; k < 512; ++k) sb += out_b[k] * fc2_w[k * 5 + j];
      bfold[j] = sb + fc2_b[j];
    }
  } else if (sub < 143){
    int s = sub - 138;             // 0..4
    if (s < 2){
      int d = s * 256 + t;
      float acc = 0.f;
      for (int j = 0; j < 512; ++j) acc += sq_w[(long)d * 512 + j] * sk_b[j];
      W2buf[(long)d * W2LD + 512] = acc;
      for (int cc = 513; cc < W2LD; ++cc) W2buf[(long)d * W2LD + cc] = 0.f;
    } else if (s < 4){
      int e = (s - 2) * 256 + t;
      float acc = 0.f;
      for (int j = 0; j < 512; ++j) acc += skw[(long)e * 512 + j] * sq_b[j];
      v2[e] = acc;
    } else {
      __shared__ float g[256];
      g[t] = sq_b[t] * sk_b[t] + sq_b[t + 256] * sk_b[t + 256];
      __syncthreads();
      for (int d = 128; d >= 1; d >>= 1){
        if (t < d) g[t] += g[t + d];
        __syncthreads();
      }
      if (t == 0) gbuf[0] = g[0];
    }
  } else if (sub < 399){
    // wqk: W_qk[h*512+d'][d] = 0.125 * sum_e kv_w[d'][h*64+e]*q_w[d][h*64+e]
    int bx = sub - 143;
    int h = bx >> 5, rem2 = bx & 31, dp = rem2 >> 2, dd = rem2 & 3;
    int dpr0 = dp * 64, dd0 = dd * 128;
    float (*Akv)[65] = (float(*)[65])sm;
    float (*Bq)[65]  = (float(*)[65])(sm + 64 * 65);
    for (int idx = t; idx < 64 * 64; idx += 256){
      int r = idx >> 6, e = idx & 63;
      Akv[r][e] = kvw[(long)(dpr0 + r) * NKV + h * 64 + e];
    }
    for (int idx = t; idx < 128 * 64; idx += 256){
      int r = idx >> 6, e = idx & 63;
      Bq[r][e] = q_w[(long)(dd0 + r) * 512 + h * 64 + e];
    }
    __syncthreads();
    int ty = t >> 4, tx = t & 15;
    float acc[4][8] = {};
    for (int e = 0; e < 64; ++e){
      float a0 = Akv[ty * 4 + 0][e], a1 = Akv[ty * 4 + 1][e];
      float a2 = Akv[ty * 4 + 2][e], a3 = Akv[ty * 4 + 3][e];
      float b[8];
#pragma unroll
      for (int v = 0; v < 8; ++v) b[v] = Bq[tx * 8 + v][e];
#pragma unroll
      for (int v = 0; v < 8; ++v){
        acc[0][v] += a0 * b[v];
        acc[1][v] += a1 * b[v];
        acc[2][v] += a2 * b[v];
        acc[3][v] += a3 * b[v];
      }
    }
#pragma unroll
    for (int u = 0; u < 4; ++u)
#pragma unroll
      for (int v = 0; v < 8; ++v)
        wqk[(long)(h * 512 + dpr0 + ty * 4 + u) * 512 + dd0 + tx * 8 + v] =
            (unsigned short)f2bf(acc[u][v] * 0.125f);
  } else {
    long idx = (long)(sub - 399) * 256 + t;
    float4 v = *(const float4*)(queries + idx * 4);
    ushort4 o;
    o.x = (unsigned short)f2bf(v.x);
    o.y = (unsigned short)f2bf(v.y);
    o.z = (unsigned short)f2bf(v.z);
    o.w = (unsigned short)f2bf(v.w);
    *(ushort4*)(qb + idx * 4) = o;
  }
}

// ---------------- psetup: PB[64][512]: rows 0..39 = P (V-fold), rest zero ----------------
__global__ __launch_bounds__(512) void psetup_kernel(const float* __restrict__ kvw,
                                                     const float* __restrict__ Wf,
                                                     unsigned short* __restrict__ PB){
  int row = blockIdx.x;           // 0..63
  int d = threadIdx.x;            // 0..511
  unsigned short v = 0;
  if (row < 40){
    int h = row / 5, j = row - h * 5;
    const float* kr = kvw + (long)d * NKV + 512 + h * 64;
    const float* wr = Wf + (long)(h * 64) * 5 + j;
    float s = 0.f;
#pragma unroll
    for (int e = 0; e < 64; ++e) s += kr[e] * wr[e * 5];
    v = (unsigned short)f2bf(s);
  }
  PB[(long)row * 512 + d] = v;
}

// ---------------- gemm_nn2: C = A[M][K] @ B[K][N] * scale, 2 rows/wave ----------------
__global__ __launch_bounds__(256) void gemm_nn2(const float* __restrict__ A, int lda,
                                                const float* __restrict__ B, int ldb,
                                                float* __restrict__ C, int ldc,
                                                int K, float scale){
  int tid = threadIdx.x;
  int lane = tid & 63, w = tid >> 6;
  int r0 = blockIdx.x * 8 + w * 2;
  int n  = blockIdx.y * 64 + lane;
  const float* a0 = A + (long)r0 * lda;
  const float* bp = B + n;
  float acc0 = 0.f, acc1 = 0.f;
#pragma unroll 4
  for (int k = 0; k < K; k += 4){
    float b0 = bp[(long)k * ldb];
    float b1 = bp[(long)(k + 1) * ldb];
    float b2 = bp[(long)(k + 2) * ldb];
    float b3 = bp[(long)(k + 3) * ldb];
    float4 a;
    a = *(const float4*)(a0 + k);
    acc0 += a.x * b0 + a.y * b1 + a.z * b2 + a.w * b3;
    a = *(const float4*)(a0 + lda + k);
    acc1 += a.x * b0 + a.y * b1 + a.z * b2 + a.w * b3;
  }
  C[(long)r0 * ldc + n]       = acc0 * scale;
  C[(long)(r0 + 1) * ldc + n] = acc1 * scale;
}

// ---------------- prepsum: memories -> summ + chunkden + bf16 (mem+pos), 16B stores ----------------
__global__ __launch_bounds__(512) void prepsum_kernel(const float* __restrict__ memories,
                                                      const float* __restrict__ pos,
                                                      const void* __restrict__ mask,
                                                      const int* __restrict__ flagp,
                                                      unsigned short* __restrict__ abf_all,
                                                      float* __restrict__ summ,
                                                      float* __restrict__ chunkden){
  int n = blockIdx.x, b = blockIdx.y;
  int t = threadIdx.x;
  unsigned short* abf = abf_all + (long)b * MPAD * 512;
  if (n == NCHUNK){
    for (int idx = t; idx < 96 * 128; idx += 512){
      ushort4 z = {0, 0, 0, 0};
      *(ushort4*)(abf + (long)(NMEM + (idx >> 7)) * 512 + (long)(idx & 127) * 4) = z;
    }
    return;
  }
  long mbase = (long)b * NMEM + (long)n * CHUNK;
  int flag = *flagp;
  bool mybit = mask_at(mask, flag, mbase + (t & 31));
  unsigned int m32 = (unsigned int)__ballot(mybit);
  float den = (float)__popc(m32);
  int rh = t >> 6;               // 0..7
  int c8 = t & 63;               // 8-elem col group
  const float* base = memories + mbase * HID + c8 * 8;
  const float* pbase = pos + c8 * 8;
  float4 va[4], vb[4], pa[4], pb[4];
#pragma unroll
  for (int j = 0; j < 4; ++j){
    va[j] = *(const float4*)(base + (long)(rh + 8 * j) * HID);
    vb[j] = *(const float4*)(base + (long)(rh + 8 * j) * HID + 4);
  }
#pragma unroll
  for (int j = 0; j < 4; ++j){
    pa[j] = *(const float4*)(pbase + (rh + 8 * j) * HID);
    pb[j] = *(const float4*)(pbase + (rh + 8 * j) * HID + 4);
  }
#pragma unroll
  for (int j = 0; j < 4; ++j){
    union { unsigned short u[8]; int4 v; } o;
    o.u[0] = (unsigned short)f2bf(va[j].x + pa[j].x);
    o.u[1] = (unsigned short)f2bf(va[j].y + pa[j].y);
    o.u[2] = (unsigned short)f2bf(va[j].z + pa[j].z);
    o.u[3] = (unsigned short)f2bf(va[j].w + pa[j].w);
    o.u[4] = (unsigned short)f2bf(vb[j].x + pb[j].x);
    o.u[5] = (unsigned short)f2bf(vb[j].y + pb[j].y);
    o.u[6] = (unsigned short)f2bf(vb[j].z + pb[j].z);
    o.u[7] = (unsigned short)f2bf(vb[j].w + pb[j].w);
    *(int4*)(abf + (long)(n * CHUNK + rh + 8 * j) * 512 + c8 * 8) = o.v;
  }
  float acc[8] = {};
#pragma unroll
  for (int j = 0; j < 4; ++j){
    if (m32 & (1u << (rh + 8 * j))){
      acc[0] += va[j].x; acc[1] += va[j].y; acc[2] += va[j].z; acc[3] += va[j].w;
      acc[4] += vb[j].x; acc[5] += vb[j].y; acc[6] += vb[j].z; acc[7] += vb[j].w;
    }
  }
  __shared__ float red[512][9];
#pragma unroll
  for (int k = 0; k < 8; ++k) red[t][k] = acc[k];
  __syncthreads();
  if (rh == 0){
    float s[8] = {};
    for (int g = 0; g < 8; ++g)
#pragma unroll
      for (int k = 0; k < 8; ++k) s[k] += red[g * 64 + c8][k];
    float dv = den + 1e-5f;
    float4 s0 = {s[0] / dv, s[1] / dv, s[2] / dv, s[3] / dv};
    float4 s1 = {s[4] / dv, s[5] / dv, s[6] / dv, s[7] / dv};
    float* srow = summ + ((long)b * NCHUNK + n) * 512 + c8 * 8;
    *(float4*)srow = s0;
    *(float4*)(srow + 4) = s1;
    if (t == 0) chunkden[b * NCHUNK + n] = den;
  }
}

// ---------------- gt_gemm: blocks [0,316) ggemm; [316,444) tgemm. Shared 40KB LDS pool ----------------
__global__ __launch_bounds__(256) void gt_gemm(const unsigned short* __restrict__ abf_all,
                                               const unsigned short* __restrict__ PB,
                                               unsigned short* __restrict__ g_all,
                                               const unsigned short* __restrict__ Aq,
                                               const unsigned short* __restrict__ Bw,
                                               float* __restrict__ T){
  __shared__ unsigned short pool[20480];
  int blk = blockIdx.x;
  int tid = threadIdx.x, wid = tid >> 6, lane = tid & 63;
  int lr = lane & 15, lg = lane >> 4;
  int scol = (lane & 3) << 3;
  int srow = wid * 16 + (lane >> 2);

  if (blk < 316){
    // ===== ggemm: G = abf @ PB^T, 256 rows x 64 cols =====
    int bb = blk / 79, g = blk - bb * 79;
    const unsigned short* A = abf_all + (size_t)bb * MPAD * 512;
    unsigned short* gout = g_all + (size_t)bb * MPAD * GLD;
    unsigned short* As[2] = { pool, pool + 8192 };
    unsigned short* Bs[2] = { pool + 16384, pool + 18432 };
    long rbase = (long)g * 256 + srow;
    long ra0 = rbase;       if (ra0 > MPAD - 1) ra0 = MPAD - 1;
    long ra1 = rbase + 64;  if (ra1 > MPAD - 1) ra1 = MPAD - 1;
    long ra2 = rbase + 128; if (ra2 > MPAD - 1) ra2 = MPAD - 1;
    long ra3 = rbase + 192; if (ra3 > MPAD - 1) ra3 = MPAD - 1;
    const unsigned short* gA0 = A + ra0 * 512 + scol;
    const unsigned short* gA1 = A + ra1 * 512 + scol;
    const unsigned short* gA2 = A + ra2 * 512 + scol;
    const unsigned short* gA3 = A + ra3 * 512 + scol;
    const unsigned short* gB0 = PB + (long)srow * 512 + scol;
    int lA0 = (wid * 16) * 32, lA1 = (64 + wid * 16) * 32;
    int lA2 = (128 + wid * 16) * 32, lA3 = (192 + wid * 16) * 32;
    int lB0 = (wid * 16) * 32;

    f32x4 acc[4][4];
#pragma unroll
    for (int i = 0; i < 4; ++i)
#pragma unroll
      for (int j = 0; j < 4; ++j) acc[i][j] = (f32x4)0.f;

#define GSTAGE(B, K0) { gload16(gA0 + (K0), &As[B][lA0]); gload16(gA1 + (K0), &As[B][lA1]); \
                        gload16(gA2 + (K0), &As[B][lA2]); gload16(gA3 + (K0), &As[B][lA3]); \
                        gload16(gB0 + (K0), &Bs[B][lB0]); }
#define GCOMPUTE(B) { bf16x8 af[4], bfv[4]; \
  _Pragma("unroll") for (int mi = 0; mi < 4; ++mi) af[mi]  = *(const bf16x8*)&As[B][(wid * 64 + mi * 16 + lr) * 32 + lg * 8]; \
  _Pragma("unroll") for (int ni = 0; ni < 4; ++ni) bfv[ni] = *(const bf16x8*)&Bs[B][(ni * 16 + lr) * 32 + lg * 8]; \
  _Pragma("unroll") for (int mi = 0; mi < 4; ++mi) \
    _Pragma("unroll") for (int ni = 0; ni < 4; ++ni) \
      acc[mi][ni] = __builtin_amdgcn_mfma_f32_16x16x32_bf16(af[mi], bfv[ni], acc[mi][ni], 0, 0, 0); }

    GSTAGE(0, 0);
    __syncthreads();
#pragma unroll 1
    for (int tt = 0; tt < 16; tt += 2){
      if (tt + 1 < 16) GSTAGE(1, (tt + 1) * 32);
      GCOMPUTE(0);
      __syncthreads();
      if (tt + 2 < 16) GSTAGE(0, (tt + 2) * 32);
      GCOMPUTE(1);
      __syncthreads();
    }
#undef GSTAGE
#undef GCOMPUTE

#pragma unroll
    for (int mi = 0; mi < 4; ++mi)
#pragma unroll
      for (int ni = 0; ni < 4; ++ni)
#pragma unroll
        for (int rr = 0; rr < 4; ++rr){
          long gr = (long)g * 256 + wid * 64 + mi * 16 + lg * 4 + rr;
          int gn = ni * 16 + lr;
          if (gr < MPAD)
            gout[gr * GLD + gn] = (unsigned short)f2bf(acc[mi][ni][rr]);
        }
  } else {
    // ===== tgemm: T = qbf @ wqk^T (f32 out), 128x128 tiles =====
    int L2 = blk - 316;
    int panel = L2 >> 5, nb = L2 & 31;
    int m0 = panel << 7, n0 = nb << 7;
    int wr = wid >> 1, wc = wid & 1;
    unsigned short* As[2] = { pool, pool + 4096 };
    unsigned short* Bs[2] = { pool + 8192, pool + 12288 };
    const unsigned short* gA0 = Aq + (long)(m0 + srow) * 512 + scol;
    const unsigned short* gA1 = gA0 + 64 * 512;
    const unsigned short* gB0 = Bw + (long)(n0 + srow) * 512 + scol;
    const unsigned short* gB1 = gB0 + 64 * 512;
    int lofs0 = (wid * 16) * 32;
    int lofs1 = (64 + wid * 16) * 32;

    f32x4 acc[4][4];
#pragma unroll
    for (int i = 0; i < 4; ++i)
#pragma unroll
      for (int j = 0; j < 4; ++j) acc[i][j] = (f32x4)0.f;

#define TSTAGE(B, K0) { gload16(gA0 + (K0), &As[B][lofs0]); gload16(gA1 + (K0), &As[B][lofs1]); \
                        gload16(gB0 + (K0), &Bs[B][lofs0]); gload16(gB1 + (K0), &Bs[B][lofs1]); }
#define TCOMPUTE(B) { bf16x8 af[4], bfv[4]; \
  _Pragma("unroll") for (int mi = 0; mi < 4; ++mi) af[mi]  = *(const bf16x8*)&As[B][(wr * 64 + mi * 16 + lr) * 32 + lg * 8]; \
  _Pragma("unroll") for (int ni = 0; ni < 4; ++ni) bfv[ni] = *(const bf16x8*)&Bs[B][(wc * 64 + ni * 16 + lr) * 32 + lg * 8]; \
  _Pragma("unroll") for (int mi = 0; mi < 4; ++mi) \
    _Pragma("unroll") for (int ni = 0; ni < 4; ++ni) \
      acc[mi][ni] = __builtin_amdgcn_mfma_f32_16x16x32_bf16(af[mi], bfv[ni], acc[mi][ni], 0, 0, 0); }

    TSTAGE(0, 0);
    __syncthreads();
#pragma unroll 1
    for (int tt = 0; tt < 16; tt += 2){
      if (tt + 1 < 16) TSTAGE(1, (tt + 1) * 32);
      TCOMPUTE(0);
      __syncthreads();
      if (tt + 2 < 16) TSTAGE(0, (tt + 2) * 32);
      TCOMPUTE(1);
      __syncthreads();
    }
#undef TSTAGE
#undef TCOMPUTE

#pragma unroll
    for (int mi = 0; mi < 4; ++mi)
#pragma unroll
      for (int ni = 0; ni < 4; ++ni)
#pragma unroll
        for (int rr = 0; rr < 4; ++rr){
          int gr = m0 + wr * 64 + mi * 16 + lg * 4 + rr;
          int gn = n0 + wc * 64 + ni * 16 + lr;
          T[(long)gr * TLD + gn] = acc[mi][ni][rr];
        }
  }
}

// ---------------- ustb: blocks [0,576) u_ext (2 rows/wave); [576,1525) stbeta ----------------
__global__ __launch_bounds__(256) void ustb_kernel(const float* __restrict__ queries,
                                                   const float* __restrict__ W2buf,
                                                   float* __restrict__ u_ext,
                                                   const float* __restrict__ summ,
                                                   const float* __restrict__ v2,
                                                   const float* __restrict__ gbuf,
                                                   float* __restrict__ summText,
                                                   float* __restrict__ betag){
  int blk = blockIdx.x;
  int t = threadIdx.x;
  if (blk < 576){
    int ax = blk & 63, ay = blk >> 6;     // ax: row tile, ay: col tile (0..8)
    int lane = t & 63, w = t >> 6;
    int r0 = ax * 8 + w * 2;
    int n  = ay * 64 + lane;
    const float* a0 = queries + (long)r0 * 512;
    const float* bp = W2buf + n;
    float acc0 = 0.f, acc1 = 0.f;
#pragma unroll 4
    for (int k = 0; k < 512; k += 4){
      float b0 = bp[(long)k * W2LD];
      float b1 = bp[(long)(k + 1) * W2LD];
      float b2 = bp[(long)(k + 2) * W2LD];
      float b3 = bp[(long)(k + 3) * W2LD];
      float4 a;
      a = *(const float4*)(a0 + k);
      acc0 += a.x * b0 + a.y * b1 + a.z * b2 + a.w * b3;
      a = *(const float4*)(a0 + 512 + k);
      acc1 += a.x * b0 + a.y * b1 + a.z * b2 + a.w * b3;
    }
    u_ext[(long)r0 * W2LD + n]       = acc0;
    u_ext[(long)(r0 + 1) * W2LD + n] = acc1;
  } else if (blk < 896){
    __shared__ float tile[64][65];
    int b2 = blk - 576;               // 0..319
    int b = b2 / 80; int rem = b2 % 80;
    int n0 = (rem / 8) * 64, e0 = (rem % 8) * 64;
    int c = t & 63, rbase = t >> 6;
#pragma unroll
    for (int j = 0; j < 16; ++j){
      int r = rbase + j * 4;
      int n = n0 + r;
      tile[r][c] = (n < NCHUNK) ? summ[((long)b * NCHUNK + n) * 512 + e0 + c] : 0.f;
    }
    __syncthreads();
#pragma unroll
    for (int j = 0; j < 16; ++j){
      int re = rbase + j * 4;
      summText[(long)b * STROWS * LGLD + (long)(e0 + re) * LGLD + n0 + c] = tile[c][re];
    }
  } else if (blk < 900){
    int b = blk - 896;
    for (int idx = t; idx < 8 * LGLD; idx += 256){
      int e = idx / LGLD, n = idx - e * LGLD;
      summText[(long)b * STROWS * LGLD + (long)(512 + e) * LGLD + n] = (e == 0) ? 1.f : 0.f;
    }
  } else {
    int bb = blk - 900;               // 0..624
    int w = t >> 6, lane = t & 63;
    int row = bb * 4 + w;
    const float* r = summ + (long)row * 512;
    float s = 0.f;
#pragma unroll
    for (int c = 0; c < 8; ++c) s += r[lane + 64 * c] * v2[lane + 64 * c];
    for (int d = 32; d >= 1; d >>= 1) s += __shfl_xor(s, d, 64);
    if (lane == 0){
      int b = row / NCHUNK, n = row % NCHUNK;
      betag[b * LGLD + n] = s + gbuf[0];
    }
  }
}

// ---------------- logits (NN form): 2 rows/wave, grid (16,10,NB) ----------------
__global__ __launch_bounds__(256) void logits_nn(const float* __restrict__ u_ext,
                                                 const float* __restrict__ summText,
                                                 const float* __restrict__ betag,
                                                 const float* __restrict__ chunkden,
                                                 float* __restrict__ logits){
  int b = blockIdx.z;
  int tid = threadIdx.x;
  int lane = tid & 63, w = tid >> 6;
  int r0 = blockIdx.x * 8 + w * 2;
  int n  = blockIdx.y * 64 + lane;
  const float* a0 = u_ext + ((long)b * QN + r0) * W2LD;
  const float* bp = summText + (long)b * STROWS * LGLD + n;
  float acc0 = 0.f, acc1 = 0.f;
#pragma unroll 4
  for (int k = 0; k < STROWS; k += 4){
    float b0 = bp[(long)k * LGLD];
    float b1 = bp[(long)(k + 1) * LGLD];
    float b2 = bp[(long)(k + 2) * LGLD];
    float b3 = bp[(long)(k + 3) * LGLD];
    float4 a;
    a = *(const float4*)(a0 + k);
    acc0 += a.x * b0 + a.y * b1 + a.z * b2 + a.w * b3;
    a = *(const float4*)(a0 + W2LD + k);
    acc1 += a.x * b0 + a.y * b1 + a.z * b2 + a.w * b3;
  }
  if (n < NCHUNK){
    float bet = betag[b * LGLD + n];
    bool dead = (chunkden[b * NCHUNK + n] <= 0.f);
    float v0 = (acc0 + bet) * LOGIT_SCALE;
    float v1 = (acc1 + bet) * LOGIT_SCALE;
    if (dead){ v0 = v1 = -FLT_MAX; }
    long base = ((long)b * QN + r0) * LGLD + n;
    logits[base]        = v0;
    logits[base + LGLD] = v1;
  }
}

// ---------------- top-8 + softmax weights, 4 waves per (b,i) row ----------------
__global__ __launch_bounds__(256) void topk_kernel(const float* __restrict__ logits,
                                                   int* __restrict__ topi_out,
                                                   float* __restrict__ wts_out){
  int row = blockIdx.x;
  __shared__ float lds[NCHUNK];
  __shared__ float wv[4];
  __shared__ int   wi[4];
  __shared__ float topv[TOPKK];
  __shared__ int   topi[TOPKK];
  int t = threadIdx.x;
  int lane = t & 63, w = t >> 6;
  for (int idx = t; idx < NCHUNK; idx += 256) lds[idx] = logits[(long)row * LGLD + idx];
  __syncthreads();
  for (int it = 0; it < TOPKK; ++it){
    float bv = -INFINITY; int bi = 0x7fffffff;
    for (int idx = t; idx < NCHUNK; idx += 256){
      float v = lds[idx];
      if (v > bv){ bv = v; bi = idx; }
    }
    for (int d = 32; d >= 1; d >>= 1){
      float ov = __shfl_xor(bv, d, 64);
      int   oi = __shfl_xor(bi, d, 64);
      if (ov > bv || (ov == bv && oi < bi)){ bv = ov; bi = oi; }
    }
    if (lane == 0){ wv[w] = bv; wi[w] = bi; }
    __syncthreads();
    if (t == 0){
      float fb = wv[0]; int fi = wi[0];
      for (int j = 1; j < 4; ++j){
        if (wv[j] > fb || (wv[j] == fb && wi[j] < fi)){ fb = wv[j]; fi = wi[j]; }
      }
      topv[it] = fb; topi[it] = fi; lds[fi] = -INFINITY;
    }
    __syncthreads();
  }
  if (t == 0){
    float m = topv[0];
    for (int r = 1; r < TOPKK; ++r) m = fmaxf(m, topv[r]);
    float e[TOPKK], s = 0.f;
    for (int r = 0; r < TOPKK; ++r){ e[r] = expf(topv[r] - m); s += e[r]; }
    for (int r = 0; r < TOPKK; ++r){
      wts_out[(long)row * TOPKK + r] = e[r] / s;
      topi_out[(long)row * TOPKK + r] = topi[r];
    }
  }
}

// ---------------- attention: sim from T . A (LDS-staged), G-fold output ----------------
#define ALDP 516   // A_lds row stride (bf16 elems)
__global__ __launch_bounds__(256) void attn5_kernel(const float* __restrict__ T,
                                                    const unsigned short* __restrict__ abf_all,
                                                    const unsigned short* __restrict__ g_all,
                                                    const int* __restrict__ topidx,
                                                    const float* __restrict__ wts,
                                                    const void* __restrict__ mask,
                                                    const int* __restrict__ flagp,
                                                    float* __restrict__ osc5){
  int bx = blockIdx.x;
  int bb = bx >> 10, rem = bx & 1023;
  int i = rem >> 3, k = rem & 7;
  const unsigned short* abf = abf_all + (size_t)bb * MPAD * 512;
  const unsigned short* gb  = g_all + (size_t)bb * MPAD * GLD;
  int t = threadIdx.x;
  __shared__ unsigned short A_lds[32 * ALDP];
  __shared__ float T_lds[TLD];
  __shared__ float red[4][5];
  int flag = *flagp;
  long sel = ((long)(bb * QN + i)) * TOPKK + k;
  int chunk = topidx[sel];
  float w8 = wts[sel];
  const float* Trow = T + (long)(bb * QN + i) * TLD;
  for (int idx = t; idx < 1024; idx += 256)
    *(float4*)&T_lds[idx * 4] = *(const float4*)&Trow[idx * 4];
  {
    int r = t >> 3, cb = (t & 7) * 64;
    const unsigned short* src = abf + (long)(chunk * CHUNK + r) * 512 + cb;
    unsigned short* dst = &A_lds[r * ALDP + cb];
#pragma unroll
    for (int j = 0; j < 8; ++j){
      bf16x8 a8 = *(const bf16x8*)(src + j * 8);
      bf16x4 lo = {a8[0], a8[1], a8[2], a8[3]};
      bf16x4 hi = {a8[4], a8[5], a8[6], a8[7]};
      *(bf16x4*)(dst + j * 8)     = lo;
      *(bf16x4*)(dst + j * 8 + 4) = hi;
    }
  }
  __syncthreads();
  int h = t >> 5, c = t & 31;
  const unsigned short* arow = &A_lds[c * ALDP];
  const float* tp = &T_lds[h * 512];
  float s = 0.f;
#pragma unroll 4
  for (int e8 = 0; e8 < 64; ++e8){
    bf16x4 alo = *(const bf16x4*)(arow + e8 * 8);
    bf16x4 ahi = *(const bf16x4*)(arow + e8 * 8 + 4);
    float4 ta = *(const float4*)(tp + e8 * 8);
    float4 tb = *(const float4*)(tp + e8 * 8 + 4);
    s += bf2f((unsigned short)alo[0]) * ta.x + bf2f((unsigned short)alo[1]) * ta.y
       + bf2f((unsigned short)alo[2]) * ta.z + bf2f((unsigned short)alo[3]) * ta.w
       + bf2f((unsigned short)ahi[0]) * tb.x + bf2f((unsigned short)ahi[1]) * tb.y
       + bf2f((unsigned short)ahi[2]) * tb.z + bf2f((unsigned short)ahi[3]) * tb.w;
  }
  bool mv = mask_at(mask, flag, (long)bb * NMEM + (long)chunk * CHUNK + c);
  if (!mv) s = -FLT_MAX;
  float m = s;
  for (int d = 16; d >= 1; d >>= 1) m = fmaxf(m, __shfl_xor(m, d, 32));
  float p = expf(s - m);
  float su = p;
  for (int d = 16; d >= 1; d >>= 1) su += __shfl_xor(su, d, 32);
  float att = p / su;
  const unsigned short* grow = gb + (long)(chunk * CHUNK + c) * GLD + h * 5;
  float p0 = att * bf2f(grow[0]);
  float p1 = att * bf2f(grow[1]);
  float p2 = att * bf2f(grow[2]);
  float p3 = att * bf2f(grow[3]);
  float p4 = att * bf2f(grow[4]);
#pragma unroll
  for (int d = 32; d >= 1; d >>= 1){
    p0 += __shfl_xor(p0, d, 64);
    p1 += __shfl_xor(p1, d, 64);
    p2 += __shfl_xor(p2, d, 64);
    p3 += __shfl_xor(p3, d, 64);
    p4 += __shfl_xor(p4, d, 64);
  }
  int w = t >> 6, lane = t & 63;
  if (lane == 0){
    red[w][0] = p0; red[w][1] = p1; red[w][2] = p2; red[w][3] = p3; red[w][4] = p4;
  }
  __syncthreads();
  if (t < 5){
    float tot = red[0][t] + red[1][t] + red[2][t] + red[3][t];
    osc5[sel * 8 + t] = w8 * tot;
  }
}

// ---------------- final5 ----------------
__global__ __launch_bounds__(64) void final5_kernel(const float* __restrict__ osc5,
                                                    const float* __restrict__ bfold,
                                                    float* __restrict__ out){
  int bi = blockIdx.x;
  int t = threadIdx.x;
  if (t < 5){
    float a = bfold[t];
#pragma unroll
    for (int k = 0; k < TOPKK; ++k) a += osc5[((long)bi * TOPKK + k) * 8 + t];
    out[bi * 5 + t] = a;
  }
}

extern "C" void kernel_launch(void* const* d_in, const int* in_sizes, int n_in,
                              void* d_out, int out_size, void* d_ws, size_t ws_size,
                              hipStream_t stream) {
  const float* queries  = (const float*)d_in[1];
  const float* memories = (const float*)d_in[2];
  const void*  mask     = d_in[3];
  const float* sq_w = (const float*)d_in[10];
  const float* sq_b = (const float*)d_in[11];
  const float* sk_w = (const float*)d_in[12];
  const float* sk_b = (const float*)d_in[13];
  const float* q_w  = (const float*)d_in[14];
  const float* kv_w = (const float*)d_in[15];
  const float* out_w = (const float*)d_in[16];
  const float* out_b = (const float*)d_in[17];
  const float* fc2_w = (const float*)d_in[18];
  const float* fc2_b = (const float*)d_in[19];
  float* out = (float*)d_out;

  char* ws = (char*)d_ws;
  size_t off = 0;
  auto alloc = [&](size_t bytes){ size_t o = off; off += (bytes + 511) & ~(size_t)511; return o; };
  size_t o_sum  = alloc(5120000);
  size_t o_den  = alloc(10240);
  size_t o_pos  = alloc(65536);
  size_t o_wf   = alloc(10240);
  size_t o_bf   = alloc(512);
  size_t o_ti   = alloc(16384);
  size_t o_wt   = alloc(16384);
  size_t o_flag = alloc(512);
  size_t o_w2   = alloc(1179648);
  size_t o_uex  = alloc(1179648);
  size_t o_st   = alloc(5324800);
  size_t o_bg   = alloc(10240);
  size_t o_v2   = alloc(2048);
  size_t o_gm   = alloc(512);
  size_t o_lg   = alloc(1310720);
  size_t o_osc5 = alloc(131072);
  size_t o_skt  = alloc(1048576);
  size_t o_qbf  = alloc(524288);
  size_t o_wqk  = alloc(4194304);
  size_t o_T    = alloc((size_t)NB * QN * TLD * 4);
  size_t o_pb   = alloc(65536);
  size_t o_abf  = alloc((size_t)NB * MPAD * 512 * 2);
  size_t o_g    = alloc((size_t)NB * MPAD * GLD * 2);

  float* summ  = (float*)(ws + o_sum);
  float* den   = (float*)(ws + o_den);
  float* pos   = (float*)(ws + o_pos);
  float* Wf    = (float*)(ws + o_wf);
  float* bfold = (float*)(ws + o_bf);
  int*   ti    = (int*)  (ws + o_ti);
  float* wt    = (float*)(ws + o_wt);
  int*   flagp = (int*)  (ws + o_flag);
  float* W2buf = (float*)(ws + o_w2);
  float* u_ext = (float*)(ws + o_uex);
  float* summText = (float*)(ws + o_st);
  float* betag = (float*)(ws + o_bg);
  float* v2    = (float*)(ws + o_v2);
  float* gbuf  = (float*)(ws + o_gm);
  float* logit = (float*)(ws + o_lg);
  float* osc5  = (float*)(ws + o_osc5);
  float* skwT  = (float*)(ws + o_skt);
  unsigned short* qb   = (unsigned short*)(ws + o_qbf);
  unsigned short* wqk  = (unsigned short*)(ws + o_wqk);
  float* Tbuf  = (float*)(ws + o_T);
  unsigned short* PB   = (unsigned short*)(ws + o_pb);
  unsigned short* abf  = (unsigned short*)(ws + o_abf);
  unsigned short* gall = (unsigned short*)(ws + o_g);

  bigsetup_kernel<<<dim3(655), dim3(256), 0, stream>>>(
      sk_w, mask, out_w, out_b, fc2_w, fc2_b, sq_w, sq_b, sk_b, q_w, kv_w, queries,
      skwT, pos, flagp, Wf, bfold, W2buf, v2, gbuf, wqk, qb);
  psetup_kernel<<<dim3(64), dim3(512), 0, stream>>>(kv_w, Wf, PB);
  gemm_nn2<<<dim3(64, 8), dim3(256), 0, stream>>>(sq_w, 512, skwT, 512, W2buf, W2LD, 512, 1.0f);

  prepsum_kernel<<<dim3(NCHUNK + 1, NB), dim3(512), 0, stream>>>(
      memories, pos, mask, flagp, abf, summ, den);

  gt_gemm<<<dim3(444), dim3(256), 0, stream>>>(abf, PB, gall, qb, wqk, Tbuf);

  ustb_kernel<<<dim3(1525), dim3(256), 0, stream>>>(
      queries, W2buf, u_ext, summ, v2, gbuf, summText, betag);
  logits_nn<<<dim3(16, 10, NB), dim3(256), 0, stream>>>(u_ext, summText, betag, den, logit);
  topk_kernel<<<dim3(NB * QN), dim3(256), 0, stream>>>(logit, ti, wt);

  attn5_kernel<<<dim3(NB * QN * TOPKK), dim3(256), 0, stream>>>(
      Tbuf, abf, gall, ti, wt, mask, flagp, osc5);
  final5_kernel<<<dim3(NB * QN), dim3(64), 0, stream>>>(osc5, bfold, out);
}